// Round 6
// baseline (2074.720 us; speedup 1.0000x reference)
//
#include <hip/hip_runtime.h>
#include <hip/hip_fp16.h>
#include <stdint.h>

#define B_ROWS 4096
#define D_IN   1024
#define H_HID  16384
#define K_TOP  32

#define CAND_CAP 1536     // per-row candidate list capacity (mean 682, sigma 26)
#define TAU      1.0f     // fixed candidate threshold; safety net via flags+fallback
#define TK_DELTA 1e-2f    // refinement window half-width (>= 2x 12-sigma h~ error)
#define WCAP     256

typedef __attribute__((ext_vector_type(8))) _Float16 half8;
typedef __attribute__((ext_vector_type(4))) float    f32x4;

// ---------------- helpers ----------------

// f16 hi part; zero if |x| below f16 min-normal (deterministic error bound).
__device__ __forceinline__ ushort hi16(float x) {
  return (fabsf(x) >= 0x1p-14f) ? __half_as_ushort(__float2half(x)) : (ushort)0;
}

__device__ __forceinline__ void gload_lds16(const void* g, void* l) {
  __builtin_amdgcn_global_load_lds(
      (const __attribute__((address_space(1))) void*)g,
      (__attribute__((address_space(3))) void*)l, 16, 0, 0);
}

// ---------------- split kernels ----------------

__global__ __launch_bounds__(256) void split_a_kernel(const float* __restrict__ x,
                                                      ushort* __restrict__ hi) {
  const int t = blockIdx.x * 256 + threadIdx.x;
  const int base = t * 4;
  float4 v = *reinterpret_cast<const float4*>(x + base);
  ushort4 h;
  h.x = hi16(v.x); h.y = hi16(v.y); h.z = hi16(v.z); h.w = hi16(v.w);
  *reinterpret_cast<ushort4*>(hi + base) = h;
}

// W [D_IN, H_HID] f32 -> hiT [H_HID, D_IN] f16 bits + wT32 [H_HID, D_IN] f32
__global__ __launch_bounds__(256) void split_wt_kernel(const float* __restrict__ W,
                                                       ushort* __restrict__ hiT,
                                                       float* __restrict__ wT32) {
  __shared__ float tile[32][33];
  const int c0 = blockIdx.x * 32;
  const int r0 = blockIdx.y * 32;
  const int tx = threadIdx.x;
  const int ty = threadIdx.y;
#pragma unroll
  for (int i = 0; i < 32; i += 8)
    tile[ty + i][tx] = W[(size_t)(r0 + ty + i) * H_HID + c0 + tx];
  __syncthreads();
#pragma unroll
  for (int i = 0; i < 32; i += 8) {
    float v = tile[tx][ty + i];
    size_t o = (size_t)(c0 + ty + i) * D_IN + r0 + tx;
    hiT[o]  = hi16(v);
    wT32[o] = v;
  }
}

// ---------------- encoder GEMM: 256x256 tile, 8-phase pipelined ----------------
// Computes h~ = Ah @ Bh^T + b.  NO dense output: elements with v >= TAU are
// pushed to per-row candidate lists (val f32, col).  topk proves completeness
// (count >= 32) or flags the row for exact fallback.
#define NTILES 16   // 1024 / 64

__global__ __launch_bounds__(512, 2) void gemm_enc_8ph(const ushort* __restrict__ Ah,
                                                       const ushort* __restrict__ Bh,
                                                       const float* __restrict__ bias,
                                                       float2* __restrict__ cand,
                                                       int* __restrict__ cnt) {
  extern __shared__ ushort smem[];   // [2][32768]: buf*32768, B-half at +16384
  const int tid  = threadIdx.x;
  const int wid  = tid >> 6;
  const int lane = tid & 63;
  const int wr   = wid >> 2;
  const int wc   = wid & 3;
  const int tm   = blockIdx.x & 15;
  const int tn   = blockIdx.x >> 4;
  const int rowA0 = tm * 256;
  const int rowB0 = tn * 256;

  const int st_row = wid * 8 + (lane >> 3);
  const int st_lin = lane & 7;
  const int st_src = (lane & 7) ^ ((lane >> 3) & 7);
  const int fr   = lane & 15;
  const int fk   = lane >> 4;
  const int swz8 = (lane & 7) << 3;

  f32x4 acc[8][4];
#pragma unroll
  for (int i = 0; i < 8; ++i)
#pragma unroll
    for (int j = 0; j < 4; ++j) {
      f32x4 z = {0.f, 0.f, 0.f, 0.f};
      acc[i][j] = z;
    }
  half8 a[4][2], b[4][2];

#define DS_A(MH)                                                            \
  _Pragma("unroll") for (int m = 0; m < 4; ++m)                             \
  _Pragma("unroll") for (int k = 0; k < 2; ++k) {                           \
    const int r = wr * 128 + ((MH) * 4 + m) * 16 + fr;                      \
    const int idx = (r * 64 + k * 32 + fk * 8) ^ swz8;                      \
    a[m][k] = *reinterpret_cast<const half8*>(Acur + idx);                  \
  }
#define DS_B(NH)                                                            \
  _Pragma("unroll") for (int n = 0; n < 2; ++n)                             \
  _Pragma("unroll") for (int k = 0; k < 2; ++k) {                           \
    const int r = wc * 64 + ((NH) * 2 + n) * 16 + fr;                       \
    const int idx = (r * 64 + k * 32 + fk * 8) ^ swz8;                      \
    b[(NH) * 2 + n][k] = *reinterpret_cast<const half8*>(Bcur + idx);       \
  }
#define MFMA_PH(MH, NH)                                                     \
  __builtin_amdgcn_s_setprio(1);                                            \
  _Pragma("unroll") for (int m = 0; m < 4; ++m)                             \
  _Pragma("unroll") for (int n = 0; n < 2; ++n)                             \
  _Pragma("unroll") for (int k = 0; k < 2; ++k)                             \
    acc[(MH) * 4 + m][(NH) * 2 + n] = __builtin_amdgcn_mfma_f32_16x16x32_f16( \
        a[m][k], b[(NH) * 2 + n][k], acc[(MH) * 4 + m][(NH) * 2 + n], 0, 0, 0); \
  __builtin_amdgcn_s_setprio(0);
#define STAGE_A(Q)                                                          \
  gload_lds16(Ah + (size_t)(rowA0 + (Q) * 64 + st_row) * 1024 + k0 + st_src * 8, \
              Lnxt + ((Q) * 64 + st_row) * 64 + st_lin * 8)
#define STAGE_B(Q)                                                          \
  gload_lds16(Bh + (size_t)(rowB0 + (Q) * 64 + st_row) * 1024 + k0 + st_src * 8, \
              Lnxt + 16384 + ((Q) * 64 + st_row) * 64 + st_lin * 8)
#define BAR() __builtin_amdgcn_s_barrier()

  // prologue: stage tile 0 into buf0.  Order: Bq0..3, Aq0, Aq2, Aq1, Aq3.
  int k0 = 0;
  ushort* Lnxt = smem;
  STAGE_B(0); STAGE_B(1); STAGE_B(2); STAGE_B(3);
  STAGE_A(0); STAGE_A(2); STAGE_A(1); STAGE_A(3);
  asm volatile("s_waitcnt vmcnt(2)" ::: "memory");
  BAR();

#pragma unroll 1
  for (int t = 0; t < NTILES - 1; ++t) {
    const int cur = t & 1;
    const ushort* Acur = smem + cur * 32768;
    const ushort* Bcur = Acur + 16384;
    Lnxt = smem + (cur ^ 1) * 32768;
    k0 = (t + 1) << 6;

    // phase 1
    DS_A(0); DS_B(0);
    STAGE_B(0); STAGE_B(1);
    BAR();
    MFMA_PH(0, 0);
    BAR();
    // phase 2
    DS_B(1);
    STAGE_B(2); STAGE_B(3);
    BAR();
    MFMA_PH(0, 1);
    asm volatile("s_waitcnt vmcnt(4)" ::: "memory");
    BAR();
    // phase 3
    DS_A(1);
    STAGE_A(0); STAGE_A(2);
    BAR();
    MFMA_PH(1, 0);
    BAR();
    // phase 4
    STAGE_A(1); STAGE_A(3);
    BAR();
    MFMA_PH(1, 1);
    asm volatile("s_waitcnt vmcnt(2)" ::: "memory");
    BAR();
  }

  // epilogue tile (no staging)
  {
    const ushort* Acur = smem + ((NTILES - 1) & 1) * 32768;
    const ushort* Bcur = Acur + 16384;
    DS_A(0); DS_B(0);
    BAR();
    MFMA_PH(0, 0);
    BAR();
    DS_B(1);
    BAR();
    MFMA_PH(0, 1);
    asm volatile("s_waitcnt vmcnt(0)" ::: "memory");
    BAR();
    DS_A(1);
    BAR();
    MFMA_PH(1, 0);
    BAR();
    MFMA_PH(1, 1);
  }

  // epilogue: +bias; push candidates >= TAU (no dense store)
  const int ccol = lane & 15;
  const int crow = (lane >> 4) * 4;
#pragma unroll
  for (int j = 0; j < 4; ++j) {
    const int col = tn * 256 + wc * 64 + j * 16 + ccol;
    const float bv = bias[col];
#pragma unroll
    for (int i = 0; i < 8; ++i) {
      const int row0 = tm * 256 + wr * 128 + i * 16 + crow;
#pragma unroll
      for (int p = 0; p < 4; ++p) {
        const float v = acc[i][j][p] + bv;
        if (v >= TAU) {
          const int row = row0 + p;
          const int pos = atomicAdd(&cnt[row], 1);
          if (pos < CAND_CAP)
            cand[(size_t)row * CAND_CAP + pos] = make_float2(v, __int_as_float(col));
        }
      }
    }
  }
#undef DS_A
#undef DS_B
#undef MFMA_PH
#undef STAGE_A
#undef STAGE_B
#undef BAR
}

// ---------------- top-K from candidates + exact refinement + dense write ----
// One block (256 thr) per row.  If cnt in [32, CAP]: the row's h~ top-32 is
// provably inside the candidate list (all non-candidates < TAU <= Tm).
// 2-level radix (bits[30:20], [19:9]) on candidates -> 32nd-largest bucket
// [blo,bhi) (width ~6e-5).  v > bhi+D definite-in; [blo-D, bhi+D] refined
// exactly via f64 dot; everything else provably out.  Any violated invariant
// -> flags[row]=1, handled bit-exactly by fallback_kernel.
__global__ __launch_bounds__(256) void topk_cand_kernel(
    const float2* __restrict__ cand, const int* __restrict__ cnt,
    int* __restrict__ flags,
    float* __restrict__ latent,
    float* __restrict__ cvals, int* __restrict__ cidx,
    const float* __restrict__ X, const float* __restrict__ WT,
    const float* __restrict__ bias) {
  __shared__ float    sval[CAND_CAP];
  __shared__ int      sidx[CAND_CAP];
  __shared__ uint32_t hist[2048];
  __shared__ uint32_t chunkS[256];
  __shared__ float    swval[WCAP];
  __shared__ int      swidx[WCAP];
  __shared__ double   wexact[WCAP];
  __shared__ float    sel_val[K_TOP];
  __shared__ int      sel_idx[K_TOP];
  __shared__ uint32_t s_d, s_ab;
  __shared__ int      s_ndef, s_nw, s_bad;

  const int tid = threadIdx.x;
  const int row = blockIdx.x;
  const int n = cnt[row];

  if (n < K_TOP || n > CAND_CAP) {
    if (tid == 0) flags[row] = 1;
    return;
  }

  const float2* crow = cand + (size_t)row * CAND_CAP;
  for (int i = tid; i < n; i += 256) {
    const float2 c = crow[i];
    sval[i] = c.x;
    sidx[i] = __float_as_int(c.y);
  }
  __syncthreads();

  // ---- 2-level radix on candidate f32 bits (all values >= TAU > 0) ----
  uint32_t prefTop = 0, d1 = 0, needL = K_TOP;
#pragma unroll 1
  for (int level = 0; level < 2; ++level) {
    const int shift = level ? 9 : 20;
    for (int b = tid; b < 2048; b += 256) hist[b] = 0;
    __syncthreads();
    for (int i = tid; i < n; i += 256) {
      const uint32_t k = __float_as_uint(sval[i]);
      if (level == 0 || (k >> 20) == prefTop)
        atomicAdd(&hist[(k >> shift) & 2047], 1u);
    }
    __syncthreads();
    uint32_t cs = 0;
#pragma unroll
    for (int c = 0; c < 8; ++c) cs += hist[tid * 8 + c];
    chunkS[tid] = cs;
    __syncthreads();
    for (int off = 1; off < 256; off <<= 1) {
      const uint32_t v = (tid + off < 256) ? chunkS[tid + off] : 0u;
      __syncthreads();
      chunkS[tid] += v;
      __syncthreads();
    }
    {
      uint32_t cum = (tid + 1 < 256) ? chunkS[tid + 1] : 0u;
#pragma unroll
      for (int c = 7; c >= 0; --c) {
        const int bb = tid * 8 + c;
        const uint32_t nxt = cum;
        cum += hist[bb];
        if (cum >= needL && nxt < needL) { s_d = (uint32_t)bb; s_ab = nxt; }
      }
    }
    __syncthreads();
    if (level == 0) { prefTop = s_d; needL = needL - s_ab; }
    else            { d1 = s_d; }
    __syncthreads();
  }

  const uint32_t blo_bits = (prefTop << 20) | (d1 << 9);
  const float Tlo = __uint_as_float(blo_bits);
  const float Thi = __uint_as_float(blo_bits + 512u);
  const float Tp = Thi + TK_DELTA;
  const float Tm = Tlo - TK_DELTA;

  if (Tm < TAU) {   // window would extend below candidate floor (never expected)
    if (tid == 0) flags[row] = 1;
    return;
  }

  // ---- classify candidates: definite-in / window ----
  if (tid == 0) { s_ndef = 0; s_nw = 0; s_bad = 0; }
  __syncthreads();
  for (int i = tid; i < n; i += 256) {
    const float v = sval[i];
    if (v > Tp) {
      const int pos = atomicAdd(&s_ndef, 1);
      if (pos < K_TOP) {
        cvals[(size_t)row * K_TOP + pos] = v;
        cidx[(size_t)row * K_TOP + pos]  = sidx[i];
        sel_val[pos] = v;
        sel_idx[pos] = sidx[i];
      } else {
        s_bad = 1;
      }
    } else if (v >= Tm) {
      const int pos = atomicAdd(&s_nw, 1);
      if (pos < WCAP) { swval[pos] = v; swidx[pos] = sidx[i]; }
      else            { s_bad = 1; }
    }
  }
  __syncthreads();
  const int ndef = s_ndef;
  const int nw   = s_nw;
  if (s_bad || ndef >= K_TOP) {   // invariant violated (logic insurance)
    if (tid == 0) flags[row] = 1;
    return;
  }
  const int r = K_TOP - ndef;     // >= 1

  // ---- exact f64 refinement of window members ----
  {
    const int wv = tid >> 6, ln = tid & 63;
    const float* xr = X + (size_t)row * D_IN;
    for (int c = wv; c < nw; c += 4) {
      const float* wrp = WT + (size_t)swidx[c] * D_IN;
      double a = 0.0;
#pragma unroll
      for (int j = 0; j < 16; ++j)
        a += (double)xr[ln + 64 * j] * (double)wrp[ln + 64 * j];
#pragma unroll
      for (int off = 32; off; off >>= 1) a += __shfl_xor(a, off);
      if (ln == 0) wexact[c] = a + (double)bias[swidx[c]];
    }
  }
  __syncthreads();
  // rank window by (exact desc, index asc) = jax tie-break; take top r
  if (tid < nw) {
    const double ei = wexact[tid];
    const int    ii = swidx[tid];
    int rank = 0;
    for (int j = 0; j < nw; ++j) {
      const double ej = wexact[j];
      const int    ij = swidx[j];
      rank += (ej > ei) || (ej == ei && ij < ii);
    }
    if (rank < r) {
      cvals[(size_t)row * K_TOP + ndef + rank] = swval[tid];
      cidx[(size_t)row * K_TOP + ndef + rank]  = ii;
      sel_val[ndef + rank] = swval[tid];
      sel_idx[ndef + rank] = ii;
    }
  }
  __syncthreads();

  // ---- dense latent row: zeros + 32 selected ----
  float* rowp = latent + (size_t)row * H_HID;
  const float4 z4 = make_float4(0.f, 0.f, 0.f, 0.f);
  for (int i4 = tid; i4 < H_HID / 4; i4 += 256)
    reinterpret_cast<float4*>(rowp)[i4] = z4;
  __syncthreads();
  if (tid < K_TOP) rowp[sel_idx[tid]] = sel_val[tid];
}

// ---------------- exact fallback (expected-never path) ----------------
// Serially handles flagged rows bit-exactly: full f64 row compute, top-32 by
// (relu value desc, idx asc), writes latent row + cvals/cidx.
__global__ __launch_bounds__(256) void fallback_kernel(
    const int* __restrict__ flags,
    const float* __restrict__ X, const float* __restrict__ WT,
    const float* __restrict__ bias,
    float* __restrict__ latent, float* __restrict__ cvals,
    int* __restrict__ cidx, double* __restrict__ scratch) {
  __shared__ double rb[256];
  __shared__ int    ri[256];
  const int tid = threadIdx.x;
#pragma unroll 1
  for (int row = 0; row < B_ROWS; ++row) {
    if (flags[row] == 0) continue;
    const float* xr = X + (size_t)row * D_IN;
    for (int c = tid; c < H_HID; c += 256) {
      const float* wrp = WT + (size_t)c * D_IN;
      double a = (double)bias[c];
      for (int j = 0; j < D_IN; ++j)
        a += (double)xr[j] * (double)wrp[j];
      scratch[c] = fmax(a, 0.0);   // relu
    }
    float* rowp = latent + (size_t)row * H_HID;
    for (int i = tid; i < H_HID; i += 256) rowp[i] = 0.0f;
    __syncthreads();
#pragma unroll 1
    for (int k = 0; k < K_TOP; ++k) {
      double bv = -1.0; int bi = H_HID;
      for (int c = tid; c < H_HID; c += 256) {
        const double v = scratch[c];
        if (v > bv || (v == bv && c < bi)) { bv = v; bi = c; }
      }
      rb[tid] = bv; ri[tid] = bi;
      __syncthreads();
      for (int off = 128; off; off >>= 1) {
        if (tid < off) {
          if (rb[tid + off] > rb[tid] ||
              (rb[tid + off] == rb[tid] && ri[tid + off] < ri[tid])) {
            rb[tid] = rb[tid + off]; ri[tid] = ri[tid + off];
          }
        }
        __syncthreads();
      }
      if (tid == 0) {
        const int ii = ri[0];
        const float vv = (float)rb[0];
        cvals[(size_t)row * K_TOP + k] = vv;
        cidx[(size_t)row * K_TOP + k]  = ii;
        rowp[ii] = vv;
        scratch[ii] = -1.0;
      }
      __syncthreads();
    }
  }
}

// ---------------- sparse decoder ----------------
__global__ __launch_bounds__(256) void decode_kernel(const float* __restrict__ cvals,
                                                     const int* __restrict__ cidx,
                                                     const float* __restrict__ Wdec,
                                                     const float* __restrict__ bias,
                                                     float* __restrict__ recon) {
  __shared__ float sv[K_TOP];
  __shared__ int   si[K_TOP];
  const int tid = threadIdx.x;
  const int row = blockIdx.x;
  if (tid < K_TOP) {
    sv[tid] = cvals[row * K_TOP + tid];
    si[tid] = cidx[row * K_TOP + tid];
  }
  __syncthreads();
  const float4 b4 = reinterpret_cast<const float4*>(bias)[tid];
  float ax = b4.x, ay = b4.y, az = b4.z, aw = b4.w;
#pragma unroll 1
  for (int k = 0; k < K_TOP; ++k) {
    const float v = sv[k];
    const float4 w = reinterpret_cast<const float4*>(Wdec + (size_t)si[k] * D_IN)[tid];
    ax = fmaf(v, w.x, ax);
    ay = fmaf(v, w.y, ay);
    az = fmaf(v, w.z, az);
    aw = fmaf(v, w.w, aw);
  }
  reinterpret_cast<float4*>(recon + (size_t)row * D_IN)[tid] = make_float4(ax, ay, az, aw);
}

// ---------------- launch ----------------

extern "C" void kernel_launch(void* const* d_in, const int* in_sizes, int n_in,
                              void* d_out, int out_size, void* d_ws, size_t ws_size,
                              hipStream_t stream) {
  (void)in_sizes; (void)n_in; (void)out_size; (void)ws_size;
  const float* Xv     = (const float*)d_in[0];
  const float* Xt     = (const float*)d_in[1];
  const float* Wv_enc = (const float*)d_in[2];
  const float* bv_enc = (const float*)d_in[3];
  const float* Wt_enc = (const float*)d_in[4];
  const float* bt_enc = (const float*)d_in[5];
  const float* Wv_dec = (const float*)d_in[6];
  const float* bv_dec = (const float*)d_in[7];
  const float* Wt_dec = (const float*)d_in[8];
  const float* bt_dec = (const float*)d_in[9];

  float* out      = (float*)d_out;
  float* recon_v  = out;
  float* recon_t  = out + (size_t)B_ROWS * D_IN;
  float* latent_v = out + 2ull * B_ROWS * D_IN;
  float* latent_t = latent_v + (size_t)B_ROWS * H_HID;

  char* ws = (char*)d_ws;
  const size_t szA = (size_t)B_ROWS * D_IN;    // 4M elems
  const size_t szB = (size_t)H_HID * D_IN;     // 16M elems
  const size_t szC = (size_t)B_ROWS * CAND_CAP;
  ushort* Ah_v  = (ushort*)ws;
  ushort* Ah_t  = Ah_v + szA;
  ushort* Bh_v  = Ah_t + szA;
  ushort* Bh_t  = Bh_v + szB;
  float*  WT32_v = (float*)(Bh_t + szB);
  float*  WT32_t = WT32_v + szB;
  float2* cand_v = (float2*)(WT32_t + szB);
  float2* cand_t = cand_v + szC;
  int*    cnt_v   = (int*)(cand_t + szC);
  int*    cnt_t   = cnt_v + B_ROWS;
  int*    flags_v = cnt_t + B_ROWS;
  int*    flags_t = flags_v + B_ROWS;
  float*  cvals_v = (float*)(flags_t + B_ROWS);
  float*  cvals_t = cvals_v + (size_t)B_ROWS * K_TOP;
  int*    cidx_v  = (int*)(cvals_t + (size_t)B_ROWS * K_TOP);
  int*    cidx_t  = cidx_v + (size_t)B_ROWS * K_TOP;
  double* fb_scratch = (double*)(cidx_t + (size_t)B_ROWS * K_TOP);

  hipFuncSetAttribute((const void*)gemm_enc_8ph,
                      hipFuncAttributeMaxDynamicSharedMemorySize, 131072);

  // zero counters + flags (contiguous 64 KB)
  hipMemsetAsync(cnt_v, 0, 4 * B_ROWS * sizeof(int), stream);

  // splits
  split_a_kernel<<<B_ROWS * D_IN / 1024, 256, 0, stream>>>(Xv, Ah_v);
  split_a_kernel<<<B_ROWS * D_IN / 1024, 256, 0, stream>>>(Xt, Ah_t);
  dim3 tg(H_HID / 32, D_IN / 32);
  split_wt_kernel<<<tg, dim3(32, 8), 0, stream>>>(Wv_enc, Bh_v, WT32_v);
  split_wt_kernel<<<tg, dim3(32, 8), 0, stream>>>(Wt_enc, Bh_t, WT32_t);

  // vision stream
  gemm_enc_8ph<<<(B_ROWS / 256) * (H_HID / 256), 512, 131072, stream>>>(
      Ah_v, Bh_v, bv_enc, cand_v, cnt_v);
  topk_cand_kernel<<<B_ROWS, 256, 0, stream>>>(cand_v, cnt_v, flags_v, latent_v,
                                               cvals_v, cidx_v, Xv, WT32_v, bv_enc);
  fallback_kernel<<<1, 256, 0, stream>>>(flags_v, Xv, WT32_v, bv_enc,
                                         latent_v, cvals_v, cidx_v, fb_scratch);
  decode_kernel<<<B_ROWS, 256, 0, stream>>>(cvals_v, cidx_v, Wv_dec, bv_dec, recon_v);

  // text stream
  gemm_enc_8ph<<<(B_ROWS / 256) * (H_HID / 256), 512, 131072, stream>>>(
      Ah_t, Bh_t, bt_enc, cand_t, cnt_t);
  topk_cand_kernel<<<B_ROWS, 256, 0, stream>>>(cand_t, cnt_t, flags_t, latent_t,
                                               cvals_t, cidx_t, Xt, WT32_t, bt_enc);
  fallback_kernel<<<1, 256, 0, stream>>>(flags_t, Xt, WT32_t, bt_enc,
                                         latent_t, cvals_t, cidx_t, fb_scratch);
  decode_kernel<<<B_ROWS, 256, 0, stream>>>(cvals_t, cidx_t, Wt_dec, bt_dec, recon_t);
}

// Round 7
// 1304.935 us; speedup vs baseline: 1.5899x; 1.5899x over previous
//
#include <hip/hip_runtime.h>
#include <hip/hip_fp16.h>
#include <stdint.h>

#define B_ROWS 4096
#define D_IN   1024
#define H_HID  16384
#define K_TOP  32

#define CAND_CAP 1536     // per-row candidate capacity (mean 682, sigma 26)
#define SLOT     32       // per-(row, 256-col block) LDS slots (mean 10.7, sigma 3.3)
#define TAU      1.0f     // fixed candidate threshold; safety via flags+fallback
#define TK_DELTA 1e-2f    // refinement window half-width (>= 2x 12-sigma h~ error)
#define WCAP     256

typedef __attribute__((ext_vector_type(8))) _Float16 half8;
typedef __attribute__((ext_vector_type(4))) float    f32x4;

// ---------------- helpers ----------------

// f16 hi part; zero if |x| below f16 min-normal (deterministic error bound).
__device__ __forceinline__ ushort hi16(float x) {
  return (fabsf(x) >= 0x1p-14f) ? __half_as_ushort(__float2half(x)) : (ushort)0;
}

__device__ __forceinline__ void gload_lds16(const void* g, void* l) {
  __builtin_amdgcn_global_load_lds(
      (const __attribute__((address_space(1))) void*)g,
      (__attribute__((address_space(3))) void*)l, 16, 0, 0);
}

// ---------------- split kernels ----------------

__global__ __launch_bounds__(256) void split_a_kernel(const float* __restrict__ x,
                                                      ushort* __restrict__ hi) {
  const int t = blockIdx.x * 256 + threadIdx.x;
  const int base = t * 4;
  float4 v = *reinterpret_cast<const float4*>(x + base);
  ushort4 h;
  h.x = hi16(v.x); h.y = hi16(v.y); h.z = hi16(v.z); h.w = hi16(v.w);
  *reinterpret_cast<ushort4*>(hi + base) = h;
}

// W [D_IN, H_HID] f32 -> hiT [H_HID, D_IN] f16 bits + wT32 [H_HID, D_IN] f32
__global__ __launch_bounds__(256) void split_wt_kernel(const float* __restrict__ W,
                                                       ushort* __restrict__ hiT,
                                                       float* __restrict__ wT32) {
  __shared__ float tile[32][33];
  const int c0 = blockIdx.x * 32;
  const int r0 = blockIdx.y * 32;
  const int tx = threadIdx.x;
  const int ty = threadIdx.y;
#pragma unroll
  for (int i = 0; i < 32; i += 8)
    tile[ty + i][tx] = W[(size_t)(r0 + ty + i) * H_HID + c0 + tx];
  __syncthreads();
#pragma unroll
  for (int i = 0; i < 32; i += 8) {
    float v = tile[tx][ty + i];
    size_t o = (size_t)(c0 + ty + i) * D_IN + r0 + tx;
    hiT[o]  = hi16(v);
    wT32[o] = v;
  }
}

// ---------------- encoder GEMM: 256x256 tile, 8-phase pipelined ----------------
// h~ = Ah @ Bh^T + b.  No dense output: v >= TAU candidates are aggregated in
// LDS per (row, block), then ONE bulk global atomicAdd per row per block
// (fixes R6's per-element device-scope atomic hot-spot).
#define NTILES 16   // 1024 / 64

__global__ __launch_bounds__(512, 2) void gemm_enc_8ph(const ushort* __restrict__ Ah,
                                                       const ushort* __restrict__ Bh,
                                                       const float* __restrict__ bias,
                                                       float2* __restrict__ cand,
                                                       int* __restrict__ cnt,
                                                       int* __restrict__ flags) {
  extern __shared__ ushort smem[];   // [2][32768]: buf*32768, B-half at +16384
  const int tid  = threadIdx.x;
  const int wid  = tid >> 6;
  const int lane = tid & 63;
  const int wr   = wid >> 2;
  const int wc   = wid & 3;
  const int tm   = blockIdx.x & 15;
  const int tn   = blockIdx.x >> 4;
  const int rowA0 = tm * 256;
  const int rowB0 = tn * 256;

  const int st_row = wid * 8 + (lane >> 3);
  const int st_lin = lane & 7;
  const int st_src = (lane & 7) ^ ((lane >> 3) & 7);
  const int fr   = lane & 15;
  const int fk   = lane >> 4;
  const int swz8 = (lane & 7) << 3;

  f32x4 acc[8][4];
#pragma unroll
  for (int i = 0; i < 8; ++i)
#pragma unroll
    for (int j = 0; j < 4; ++j) {
      f32x4 z = {0.f, 0.f, 0.f, 0.f};
      acc[i][j] = z;
    }
  half8 a[4][2], b[4][2];

#define DS_A(MH)                                                            \
  _Pragma("unroll") for (int m = 0; m < 4; ++m)                             \
  _Pragma("unroll") for (int k = 0; k < 2; ++k) {                           \
    const int r = wr * 128 + ((MH) * 4 + m) * 16 + fr;                      \
    const int idx = (r * 64 + k * 32 + fk * 8) ^ swz8;                      \
    a[m][k] = *reinterpret_cast<const half8*>(Acur + idx);                  \
  }
#define DS_B(NH)                                                            \
  _Pragma("unroll") for (int n = 0; n < 2; ++n)                             \
  _Pragma("unroll") for (int k = 0; k < 2; ++k) {                           \
    const int r = wc * 64 + ((NH) * 2 + n) * 16 + fr;                       \
    const int idx = (r * 64 + k * 32 + fk * 8) ^ swz8;                      \
    b[(NH) * 2 + n][k] = *reinterpret_cast<const half8*>(Bcur + idx);       \
  }
#define MFMA_PH(MH, NH)                                                     \
  __builtin_amdgcn_s_setprio(1);                                            \
  _Pragma("unroll") for (int m = 0; m < 4; ++m)                             \
  _Pragma("unroll") for (int n = 0; n < 2; ++n)                             \
  _Pragma("unroll") for (int k = 0; k < 2; ++k)                             \
    acc[(MH) * 4 + m][(NH) * 2 + n] = __builtin_amdgcn_mfma_f32_16x16x32_f16( \
        a[m][k], b[(NH) * 2 + n][k], acc[(MH) * 4 + m][(NH) * 2 + n], 0, 0, 0); \
  __builtin_amdgcn_s_setprio(0);
#define STAGE_A(Q)                                                          \
  gload_lds16(Ah + (size_t)(rowA0 + (Q) * 64 + st_row) * 1024 + k0 + st_src * 8, \
              Lnxt + ((Q) * 64 + st_row) * 64 + st_lin * 8)
#define STAGE_B(Q)                                                          \
  gload_lds16(Bh + (size_t)(rowB0 + (Q) * 64 + st_row) * 1024 + k0 + st_src * 8, \
              Lnxt + 16384 + ((Q) * 64 + st_row) * 64 + st_lin * 8)
#define BAR() __builtin_amdgcn_s_barrier()

  // prologue: stage tile 0 into buf0.  Order: Bq0..3, Aq0, Aq2, Aq1, Aq3.
  int k0 = 0;
  ushort* Lnxt = smem;
  STAGE_B(0); STAGE_B(1); STAGE_B(2); STAGE_B(3);
  STAGE_A(0); STAGE_A(2); STAGE_A(1); STAGE_A(3);
  asm volatile("s_waitcnt vmcnt(2)" ::: "memory");
  BAR();

#pragma unroll 1
  for (int t = 0; t < NTILES - 1; ++t) {
    const int cur = t & 1;
    const ushort* Acur = smem + cur * 32768;
    const ushort* Bcur = Acur + 16384;
    Lnxt = smem + (cur ^ 1) * 32768;
    k0 = (t + 1) << 6;

    // phase 1
    DS_A(0); DS_B(0);
    STAGE_B(0); STAGE_B(1);
    BAR();
    MFMA_PH(0, 0);
    BAR();
    // phase 2
    DS_B(1);
    STAGE_B(2); STAGE_B(3);
    BAR();
    MFMA_PH(0, 1);
    asm volatile("s_waitcnt vmcnt(4)" ::: "memory");
    BAR();
    // phase 3
    DS_A(1);
    STAGE_A(0); STAGE_A(2);
    BAR();
    MFMA_PH(1, 0);
    BAR();
    // phase 4
    STAGE_A(1); STAGE_A(3);
    BAR();
    MFMA_PH(1, 1);
    asm volatile("s_waitcnt vmcnt(2)" ::: "memory");
    BAR();
  }

  // epilogue tile (no staging)
  {
    const ushort* Acur = smem + ((NTILES - 1) & 1) * 32768;
    const ushort* Bcur = Acur + 16384;
    DS_A(0); DS_B(0);
    BAR();
    MFMA_PH(0, 0);
    BAR();
    DS_B(1);
    BAR();
    MFMA_PH(0, 1);
    asm volatile("s_waitcnt vmcnt(0)" ::: "memory");
    BAR();
    DS_A(1);
    BAR();
    MFMA_PH(1, 0);
    BAR();
    MFMA_PH(1, 1);
  }

  // ---- epilogue: LDS-aggregated candidate push (reuse dead smem) ----
  char* sb = reinterpret_cast<char*>(smem);
  int*    lcnt  = reinterpret_cast<int*>(sb);            // [256]
  float2* lcand = reinterpret_cast<float2*>(sb + 1024);  // [256][SLOT] = 64 KB

  __syncthreads();
  if (tid < 256) lcnt[tid] = 0;
  __syncthreads();

  const int ccol = lane & 15;
  const int crow = (lane >> 4) * 4;
#pragma unroll
  for (int j = 0; j < 4; ++j) {
    const int col = tn * 256 + wc * 64 + j * 16 + ccol;
    const float bv = bias[col];
#pragma unroll
    for (int i = 0; i < 8; ++i) {
      const int lrow0 = wr * 128 + i * 16 + crow;
#pragma unroll
      for (int p = 0; p < 4; ++p) {
        const float v = acc[i][j][p] + bv;
        if (v >= TAU) {
          const int lrow = lrow0 + p;
          const int pos = atomicAdd(&lcnt[lrow], 1);
          if (pos < SLOT)
            lcand[lrow * SLOT + pos] = make_float2(v, __int_as_float(col));
        }
      }
    }
  }
  __syncthreads();

  if (tid < 256) {
    int c = lcnt[tid];
    const int grow = rowA0 + tid;
    if (c > SLOT) { flags[grow] = 1; c = SLOT; }
    if (c > 0) {
      const int base = atomicAdd(&cnt[grow], c);
      float2* dst = cand + (size_t)grow * CAND_CAP;
      for (int k = 0; k < c; ++k) {
        const int pos = base + k;
        if (pos < CAND_CAP) dst[pos] = lcand[tid * SLOT + k];
      }
      // if base+c > CAND_CAP, cnt[grow] ends > CAND_CAP -> topk flags the row
    }
  }
#undef DS_A
#undef DS_B
#undef MFMA_PH
#undef STAGE_A
#undef STAGE_B
#undef BAR
}

// ---------------- top-K from candidates + exact refinement + dense write ----
// One block (256 thr) per row.  If cnt in [32, CAP]: the row's h~ top-32 is
// provably inside the candidate list (all non-candidates < TAU <= Tm).
// 2-level radix (bits[30:20], [19:9]) -> 32nd-largest bucket [Tlo,Thi)
// (width ~6e-5).  v > Thi+D definite-in; [Tlo-D, Thi+D] refined exactly via
// f64 dot; else provably out.  Violated invariants -> flags -> fallback.
__global__ __launch_bounds__(256) void topk_cand_kernel(
    const float2* __restrict__ cand, const int* __restrict__ cnt,
    int* __restrict__ flags,
    float* __restrict__ latent,
    float* __restrict__ cvals, int* __restrict__ cidx,
    const float* __restrict__ X, const float* __restrict__ WT,
    const float* __restrict__ bias) {
  __shared__ float    sval[CAND_CAP];
  __shared__ int      sidx[CAND_CAP];
  __shared__ uint32_t hist[2048];
  __shared__ uint32_t chunkS[256];
  __shared__ float    swval[WCAP];
  __shared__ int      swidx[WCAP];
  __shared__ double   wexact[WCAP];
  __shared__ float    sel_val[K_TOP];
  __shared__ int      sel_idx[K_TOP];
  __shared__ uint32_t s_d, s_ab;
  __shared__ int      s_ndef, s_nw, s_bad;

  const int tid = threadIdx.x;
  const int row = blockIdx.x;
  const int n = cnt[row];

  if (n < K_TOP || n > CAND_CAP) {
    if (tid == 0) flags[row] = 1;
    return;
  }

  const float2* crow = cand + (size_t)row * CAND_CAP;
  for (int i = tid; i < n; i += 256) {
    const float2 c = crow[i];
    sval[i] = c.x;
    sidx[i] = __float_as_int(c.y);
  }
  __syncthreads();

  // ---- 2-level radix on candidate f32 bits (all values >= TAU > 0) ----
  uint32_t prefTop = 0, d1 = 0, needL = K_TOP;
#pragma unroll 1
  for (int level = 0; level < 2; ++level) {
    const int shift = level ? 9 : 20;
    for (int b = tid; b < 2048; b += 256) hist[b] = 0;
    __syncthreads();
    for (int i = tid; i < n; i += 256) {
      const uint32_t k = __float_as_uint(sval[i]);
      if (level == 0 || (k >> 20) == prefTop)
        atomicAdd(&hist[(k >> shift) & 2047], 1u);
    }
    __syncthreads();
    uint32_t cs = 0;
#pragma unroll
    for (int c = 0; c < 8; ++c) cs += hist[tid * 8 + c];
    chunkS[tid] = cs;
    __syncthreads();
    for (int off = 1; off < 256; off <<= 1) {
      const uint32_t v = (tid + off < 256) ? chunkS[tid + off] : 0u;
      __syncthreads();
      chunkS[tid] += v;
      __syncthreads();
    }
    {
      uint32_t cum = (tid + 1 < 256) ? chunkS[tid + 1] : 0u;
#pragma unroll
      for (int c = 7; c >= 0; --c) {
        const int bb = tid * 8 + c;
        const uint32_t nxt = cum;
        cum += hist[bb];
        if (cum >= needL && nxt < needL) { s_d = (uint32_t)bb; s_ab = nxt; }
      }
    }
    __syncthreads();
    if (level == 0) { prefTop = s_d; needL = needL - s_ab; }
    else            { d1 = s_d; }
    __syncthreads();
  }

  const uint32_t blo_bits = (prefTop << 20) | (d1 << 9);
  const float Tlo = __uint_as_float(blo_bits);
  const float Thi = __uint_as_float(blo_bits + 512u);
  const float Tp = Thi + TK_DELTA;
  const float Tm = Tlo - TK_DELTA;

  if (Tm < TAU) {   // window extends below candidate floor (never expected)
    if (tid == 0) flags[row] = 1;
    return;
  }

  // ---- classify candidates: definite-in / window ----
  if (tid == 0) { s_ndef = 0; s_nw = 0; s_bad = 0; }
  __syncthreads();
  for (int i = tid; i < n; i += 256) {
    const float v = sval[i];
    if (v > Tp) {
      const int pos = atomicAdd(&s_ndef, 1);
      if (pos < K_TOP) {
        cvals[(size_t)row * K_TOP + pos] = v;
        cidx[(size_t)row * K_TOP + pos]  = sidx[i];
        sel_val[pos] = v;
        sel_idx[pos] = sidx[i];
      } else {
        s_bad = 1;
      }
    } else if (v >= Tm) {
      const int pos = atomicAdd(&s_nw, 1);
      if (pos < WCAP) { swval[pos] = v; swidx[pos] = sidx[i]; }
      else            { s_bad = 1; }
    }
  }
  __syncthreads();
  const int ndef = s_ndef;
  const int nw   = s_nw;
  if (s_bad || ndef >= K_TOP) {
    if (tid == 0) flags[row] = 1;
    return;
  }
  const int r = K_TOP - ndef;     // >= 1

  // ---- exact f64 refinement of window members ----
  {
    const int wv = tid >> 6, ln = tid & 63;
    const float* xr = X + (size_t)row * D_IN;
    for (int c = wv; c < nw; c += 4) {
      const float* wrp = WT + (size_t)swidx[c] * D_IN;
      double a = 0.0;
#pragma unroll
      for (int j = 0; j < 16; ++j)
        a += (double)xr[ln + 64 * j] * (double)wrp[ln + 64 * j];
#pragma unroll
      for (int off = 32; off; off >>= 1) a += __shfl_xor(a, off);
      if (ln == 0) wexact[c] = a + (double)bias[swidx[c]];
    }
  }
  __syncthreads();
  // rank window by (exact desc, index asc) = jax tie-break; take top r
  if (tid < nw) {
    const double ei = wexact[tid];
    const int    ii = swidx[tid];
    int rank = 0;
    for (int j = 0; j < nw; ++j) {
      const double ej = wexact[j];
      const int    ij = swidx[j];
      rank += (ej > ei) || (ej == ei && ij < ii);
    }
    if (rank < r) {
      cvals[(size_t)row * K_TOP + ndef + rank] = swval[tid];
      cidx[(size_t)row * K_TOP + ndef + rank]  = ii;
      sel_val[ndef + rank] = swval[tid];
      sel_idx[ndef + rank] = ii;
    }
  }
  __syncthreads();

  // ---- dense latent row: zeros + 32 selected ----
  float* rowp = latent + (size_t)row * H_HID;
  const float4 z4 = make_float4(0.f, 0.f, 0.f, 0.f);
  for (int i4 = tid; i4 < H_HID / 4; i4 += 256)
    reinterpret_cast<float4*>(rowp)[i4] = z4;
  __syncthreads();
  if (tid < K_TOP) rowp[sel_idx[tid]] = sel_val[tid];
}

// ---------------- exact fallback (expected-never path) ----------------
__global__ __launch_bounds__(256) void fallback_kernel(
    const int* __restrict__ flags,
    const float* __restrict__ X, const float* __restrict__ WT,
    const float* __restrict__ bias,
    float* __restrict__ latent, float* __restrict__ cvals,
    int* __restrict__ cidx, double* __restrict__ scratch) {
  __shared__ double rb[256];
  __shared__ int    ri[256];
  const int tid = threadIdx.x;
#pragma unroll 1
  for (int row = 0; row < B_ROWS; ++row) {
    if (flags[row] == 0) continue;
    const float* xr = X + (size_t)row * D_IN;
    for (int c = tid; c < H_HID; c += 256) {
      const float* wrp = WT + (size_t)c * D_IN;
      double a = (double)bias[c];
      for (int j = 0; j < D_IN; ++j)
        a += (double)xr[j] * (double)wrp[j];
      scratch[c] = fmax(a, 0.0);   // relu
    }
    float* rowp = latent + (size_t)row * H_HID;
    for (int i = tid; i < H_HID; i += 256) rowp[i] = 0.0f;
    __syncthreads();
#pragma unroll 1
    for (int k = 0; k < K_TOP; ++k) {
      double bv = -1.0; int bi = H_HID;
      for (int c = tid; c < H_HID; c += 256) {
        const double v = scratch[c];
        if (v > bv || (v == bv && c < bi)) { bv = v; bi = c; }
      }
      rb[tid] = bv; ri[tid] = bi;
      __syncthreads();
      for (int off = 128; off; off >>= 1) {
        if (tid < off) {
          if (rb[tid + off] > rb[tid] ||
              (rb[tid + off] == rb[tid] && ri[tid + off] < ri[tid])) {
            rb[tid] = rb[tid + off]; ri[tid] = ri[tid + off];
          }
        }
        __syncthreads();
      }
      if (tid == 0) {
        const int ii = ri[0];
        const float vv = (float)rb[0];
        cvals[(size_t)row * K_TOP + k] = vv;
        cidx[(size_t)row * K_TOP + k]  = ii;
        rowp[ii] = vv;
        scratch[ii] = -1.0;
      }
      __syncthreads();
    }
  }
}

// ---------------- sparse decoder ----------------
__global__ __launch_bounds__(256) void decode_kernel(const float* __restrict__ cvals,
                                                     const int* __restrict__ cidx,
                                                     const float* __restrict__ Wdec,
                                                     const float* __restrict__ bias,
                                                     float* __restrict__ recon) {
  __shared__ float sv[K_TOP];
  __shared__ int   si[K_TOP];
  const int tid = threadIdx.x;
  const int row = blockIdx.x;
  if (tid < K_TOP) {
    sv[tid] = cvals[row * K_TOP + tid];
    si[tid] = cidx[row * K_TOP + tid];
  }
  __syncthreads();
  const float4 b4 = reinterpret_cast<const float4*>(bias)[tid];
  float ax = b4.x, ay = b4.y, az = b4.z, aw = b4.w;
#pragma unroll 1
  for (int k = 0; k < K_TOP; ++k) {
    const float v = sv[k];
    const float4 w = reinterpret_cast<const float4*>(Wdec + (size_t)si[k] * D_IN)[tid];
    ax = fmaf(v, w.x, ax);
    ay = fmaf(v, w.y, ay);
    az = fmaf(v, w.z, az);
    aw = fmaf(v, w.w, aw);
  }
  reinterpret_cast<float4*>(recon + (size_t)row * D_IN)[tid] = make_float4(ax, ay, az, aw);
}

// ---------------- launch ----------------

extern "C" void kernel_launch(void* const* d_in, const int* in_sizes, int n_in,
                              void* d_out, int out_size, void* d_ws, size_t ws_size,
                              hipStream_t stream) {
  (void)in_sizes; (void)n_in; (void)out_size; (void)ws_size;
  const float* Xv     = (const float*)d_in[0];
  const float* Xt     = (const float*)d_in[1];
  const float* Wv_enc = (const float*)d_in[2];
  const float* bv_enc = (const float*)d_in[3];
  const float* Wt_enc = (const float*)d_in[4];
  const float* bt_enc = (const float*)d_in[5];
  const float* Wv_dec = (const float*)d_in[6];
  const float* bv_dec = (const float*)d_in[7];
  const float* Wt_dec = (const float*)d_in[8];
  const float* bt_dec = (const float*)d_in[9];

  float* out      = (float*)d_out;
  float* recon_v  = out;
  float* recon_t  = out + (size_t)B_ROWS * D_IN;
  float* latent_v = out + 2ull * B_ROWS * D_IN;
  float* latent_t = latent_v + (size_t)B_ROWS * H_HID;

  char* ws = (char*)d_ws;
  const size_t szA = (size_t)B_ROWS * D_IN;    // 4M elems
  const size_t szB = (size_t)H_HID * D_IN;     // 16M elems
  const size_t szC = (size_t)B_ROWS * CAND_CAP;
  ushort* Ah_v  = (ushort*)ws;
  ushort* Ah_t  = Ah_v + szA;
  ushort* Bh_v  = Ah_t + szA;
  ushort* Bh_t  = Bh_v + szB;
  float*  WT32_v = (float*)(Bh_t + szB);
  float*  WT32_t = WT32_v + szB;
  float2* cand_v = (float2*)(WT32_t + szB);
  float2* cand_t = cand_v + szC;
  int*    cnt_v   = (int*)(cand_t + szC);
  int*    cnt_t   = cnt_v + B_ROWS;
  int*    flags_v = cnt_t + B_ROWS;
  int*    flags_t = flags_v + B_ROWS;
  float*  cvals_v = (float*)(flags_t + B_ROWS);
  float*  cvals_t = cvals_v + (size_t)B_ROWS * K_TOP;
  int*    cidx_v  = (int*)(cvals_t + (size_t)B_ROWS * K_TOP);
  int*    cidx_t  = cidx_v + (size_t)B_ROWS * K_TOP;
  double* fb_scratch = (double*)(cidx_t + (size_t)B_ROWS * K_TOP);

  hipFuncSetAttribute((const void*)gemm_enc_8ph,
                      hipFuncAttributeMaxDynamicSharedMemorySize, 131072);

  // zero counters + flags (contiguous 64 KB)
  hipMemsetAsync(cnt_v, 0, 4 * B_ROWS * sizeof(int), stream);

  // splits
  split_a_kernel<<<B_ROWS * D_IN / 1024, 256, 0, stream>>>(Xv, Ah_v);
  split_a_kernel<<<B_ROWS * D_IN / 1024, 256, 0, stream>>>(Xt, Ah_t);
  dim3 tg(H_HID / 32, D_IN / 32);
  split_wt_kernel<<<tg, dim3(32, 8), 0, stream>>>(Wv_enc, Bh_v, WT32_v);
  split_wt_kernel<<<tg, dim3(32, 8), 0, stream>>>(Wt_enc, Bh_t, WT32_t);

  // vision stream
  gemm_enc_8ph<<<(B_ROWS / 256) * (H_HID / 256), 512, 131072, stream>>>(
      Ah_v, Bh_v, bv_enc, cand_v, cnt_v, flags_v);
  topk_cand_kernel<<<B_ROWS, 256, 0, stream>>>(cand_v, cnt_v, flags_v, latent_v,
                                               cvals_v, cidx_v, Xv, WT32_v, bv_enc);
  fallback_kernel<<<1, 256, 0, stream>>>(flags_v, Xv, WT32_v, bv_enc,
                                         latent_v, cvals_v, cidx_v, fb_scratch);
  decode_kernel<<<B_ROWS, 256, 0, stream>>>(cvals_v, cidx_v, Wv_dec, bv_dec, recon_v);

  // text stream
  gemm_enc_8ph<<<(B_ROWS / 256) * (H_HID / 256), 512, 131072, stream>>>(
      Ah_t, Bh_t, bt_enc, cand_t, cnt_t, flags_t);
  topk_cand_kernel<<<B_ROWS, 256, 0, stream>>>(cand_t, cnt_t, flags_t, latent_t,
                                               cvals_t, cidx_t, Xt, WT32_t, bt_enc);
  fallback_kernel<<<1, 256, 0, stream>>>(flags_t, Xt, WT32_t, bt_enc,
                                         latent_t, cvals_t, cidx_t, fb_scratch);
  decode_kernel<<<B_ROWS, 256, 0, stream>>>(cvals_t, cidx_t, Wt_dec, bt_dec, recon_t);
}

// Round 8
// 736.802 us; speedup vs baseline: 2.8158x; 1.7711x over previous
//
#include <hip/hip_runtime.h>
#include <hip/hip_fp16.h>
#include <stdint.h>

#define B_ROWS 4096
#define D_IN   1024
#define H_HID  16384
#define K_TOP  32

#define CAND_CAP 1536     // per-row candidate capacity (mean 682, sigma 26)
#define SLOT     32       // per-(row, 256-col block) LDS slots (mean 10.7, sigma 3.3)
#define TAU      1.0f     // fixed candidate threshold; safety via flags+fallback
#define TK_DELTA 1e-2f    // refinement window half-width (>= 2x 12-sigma h~ error)
#define WCAP     256

typedef __attribute__((ext_vector_type(8))) _Float16 half8;
typedef __attribute__((ext_vector_type(4))) float    f32x4;

// ---------------- helpers ----------------

// f16 hi part; zero if |x| below f16 min-normal (deterministic error bound).
__device__ __forceinline__ ushort hi16(float x) {
  return (fabsf(x) >= 0x1p-14f) ? __half_as_ushort(__float2half(x)) : (ushort)0;
}

__device__ __forceinline__ void gload_lds16(const void* g, void* l) {
  __builtin_amdgcn_global_load_lds(
      (const __attribute__((address_space(1))) void*)g,
      (__attribute__((address_space(3))) void*)l, 16, 0, 0);
}

// ---------------- split kernels ----------------

__global__ __launch_bounds__(256) void split_a_kernel(const float* __restrict__ x,
                                                      ushort* __restrict__ hi) {
  const int t = blockIdx.x * 256 + threadIdx.x;
  const int base = t * 4;
  float4 v = *reinterpret_cast<const float4*>(x + base);
  ushort4 h;
  h.x = hi16(v.x); h.y = hi16(v.y); h.z = hi16(v.z); h.w = hi16(v.w);
  *reinterpret_cast<ushort4*>(hi + base) = h;
}

// W [D_IN, H_HID] f32 -> hiT [H_HID, D_IN] f16 bits + wT32 [H_HID, D_IN] f32
__global__ __launch_bounds__(256) void split_wt_kernel(const float* __restrict__ W,
                                                       ushort* __restrict__ hiT,
                                                       float* __restrict__ wT32) {
  __shared__ float tile[32][33];
  const int c0 = blockIdx.x * 32;
  const int r0 = blockIdx.y * 32;
  const int tx = threadIdx.x;
  const int ty = threadIdx.y;
#pragma unroll
  for (int i = 0; i < 32; i += 8)
    tile[ty + i][tx] = W[(size_t)(r0 + ty + i) * H_HID + c0 + tx];
  __syncthreads();
#pragma unroll
  for (int i = 0; i < 32; i += 8) {
    float v = tile[tx][ty + i];
    size_t o = (size_t)(c0 + ty + i) * D_IN + r0 + tx;
    hiT[o]  = hi16(v);
    wT32[o] = v;
  }
}

// ---------------- encoder GEMM: 256x256 tile, 8-phase pipelined ----------------
// h~ = Ah @ Bh^T + b.  No dense output: v >= TAU candidates are aggregated in
// LDS per (row, block), then ONE bulk global atomicAdd per row per block.
#define NTILES 16   // 1024 / 64

__global__ __launch_bounds__(512, 2) void gemm_enc_8ph(const ushort* __restrict__ Ah,
                                                       const ushort* __restrict__ Bh,
                                                       const float* __restrict__ bias,
                                                       float2* __restrict__ cand,
                                                       int* __restrict__ cnt,
                                                       int* __restrict__ flags) {
  extern __shared__ ushort smem[];   // [2][32768]: buf*32768, B-half at +16384
  const int tid  = threadIdx.x;
  const int wid  = tid >> 6;
  const int lane = tid & 63;
  const int wr   = wid >> 2;
  const int wc   = wid & 3;
  const int tm   = blockIdx.x & 15;
  const int tn   = blockIdx.x >> 4;
  const int rowA0 = tm * 256;
  const int rowB0 = tn * 256;

  const int st_row = wid * 8 + (lane >> 3);
  const int st_lin = lane & 7;
  const int st_src = (lane & 7) ^ ((lane >> 3) & 7);
  const int fr   = lane & 15;
  const int fk   = lane >> 4;
  const int swz8 = (lane & 7) << 3;

  f32x4 acc[8][4];
#pragma unroll
  for (int i = 0; i < 8; ++i)
#pragma unroll
    for (int j = 0; j < 4; ++j) {
      f32x4 z = {0.f, 0.f, 0.f, 0.f};
      acc[i][j] = z;
    }
  half8 a[4][2], b[4][2];

#define DS_A(MH)                                                            \
  _Pragma("unroll") for (int m = 0; m < 4; ++m)                             \
  _Pragma("unroll") for (int k = 0; k < 2; ++k) {                           \
    const int r = wr * 128 + ((MH) * 4 + m) * 16 + fr;                      \
    const int idx = (r * 64 + k * 32 + fk * 8) ^ swz8;                      \
    a[m][k] = *reinterpret_cast<const half8*>(Acur + idx);                  \
  }
#define DS_B(NH)                                                            \
  _Pragma("unroll") for (int n = 0; n < 2; ++n)                             \
  _Pragma("unroll") for (int k = 0; k < 2; ++k) {                           \
    const int r = wc * 64 + ((NH) * 2 + n) * 16 + fr;                       \
    const int idx = (r * 64 + k * 32 + fk * 8) ^ swz8;                      \
    b[(NH) * 2 + n][k] = *reinterpret_cast<const half8*>(Bcur + idx);       \
  }
#define MFMA_PH(MH, NH)                                                     \
  __builtin_amdgcn_s_setprio(1);                                            \
  _Pragma("unroll") for (int m = 0; m < 4; ++m)                             \
  _Pragma("unroll") for (int n = 0; n < 2; ++n)                             \
  _Pragma("unroll") for (int k = 0; k < 2; ++k)                             \
    acc[(MH) * 4 + m][(NH) * 2 + n] = __builtin_amdgcn_mfma_f32_16x16x32_f16( \
        a[m][k], b[(NH) * 2 + n][k], acc[(MH) * 4 + m][(NH) * 2 + n], 0, 0, 0); \
  __builtin_amdgcn_s_setprio(0);
#define STAGE_A(Q)                                                          \
  gload_lds16(Ah + (size_t)(rowA0 + (Q) * 64 + st_row) * 1024 + k0 + st_src * 8, \
              Lnxt + ((Q) * 64 + st_row) * 64 + st_lin * 8)
#define STAGE_B(Q)                                                          \
  gload_lds16(Bh + (size_t)(rowB0 + (Q) * 64 + st_row) * 1024 + k0 + st_src * 8, \
              Lnxt + 16384 + ((Q) * 64 + st_row) * 64 + st_lin * 8)
#define BAR() __builtin_amdgcn_s_barrier()

  // prologue: stage tile 0 into buf0.  Order: Bq0..3, Aq0, Aq2, Aq1, Aq3.
  int k0 = 0;
  ushort* Lnxt = smem;
  STAGE_B(0); STAGE_B(1); STAGE_B(2); STAGE_B(3);
  STAGE_A(0); STAGE_A(2); STAGE_A(1); STAGE_A(3);
  asm volatile("s_waitcnt vmcnt(2)" ::: "memory");
  BAR();

#pragma unroll 1
  for (int t = 0; t < NTILES - 1; ++t) {
    const int cur = t & 1;
    const ushort* Acur = smem + cur * 32768;
    const ushort* Bcur = Acur + 16384;
    Lnxt = smem + (cur ^ 1) * 32768;
    k0 = (t + 1) << 6;

    // phase 1
    DS_A(0); DS_B(0);
    STAGE_B(0); STAGE_B(1);
    BAR();
    MFMA_PH(0, 0);
    BAR();
    // phase 2
    DS_B(1);
    STAGE_B(2); STAGE_B(3);
    BAR();
    MFMA_PH(0, 1);
    asm volatile("s_waitcnt vmcnt(4)" ::: "memory");
    BAR();
    // phase 3
    DS_A(1);
    STAGE_A(0); STAGE_A(2);
    BAR();
    MFMA_PH(1, 0);
    BAR();
    // phase 4
    STAGE_A(1); STAGE_A(3);
    BAR();
    MFMA_PH(1, 1);
    asm volatile("s_waitcnt vmcnt(2)" ::: "memory");
    BAR();
  }

  // epilogue tile (no staging)
  {
    const ushort* Acur = smem + ((NTILES - 1) & 1) * 32768;
    const ushort* Bcur = Acur + 16384;
    DS_A(0); DS_B(0);
    BAR();
    MFMA_PH(0, 0);
    BAR();
    DS_B(1);
    BAR();
    MFMA_PH(0, 1);
    asm volatile("s_waitcnt vmcnt(0)" ::: "memory");
    BAR();
    DS_A(1);
    BAR();
    MFMA_PH(1, 0);
    BAR();
    MFMA_PH(1, 1);
  }

  // ---- epilogue: LDS-aggregated candidate push (reuse dead smem) ----
  char* sb = reinterpret_cast<char*>(smem);
  int*    lcnt  = reinterpret_cast<int*>(sb);            // [256]
  float2* lcand = reinterpret_cast<float2*>(sb + 1024);  // [256][SLOT] = 64 KB

  __syncthreads();
  if (tid < 256) lcnt[tid] = 0;
  __syncthreads();

  const int ccol = lane & 15;
  const int crow = (lane >> 4) * 4;
#pragma unroll
  for (int j = 0; j < 4; ++j) {
    const int col = tn * 256 + wc * 64 + j * 16 + ccol;
    const float bv = bias[col];
#pragma unroll
    for (int i = 0; i < 8; ++i) {
      const int lrow0 = wr * 128 + i * 16 + crow;
#pragma unroll
      for (int p = 0; p < 4; ++p) {
        const float v = acc[i][j][p] + bv;
        if (v >= TAU) {
          const int lrow = lrow0 + p;
          const int pos = atomicAdd(&lcnt[lrow], 1);
          if (pos < SLOT)
            lcand[lrow * SLOT + pos] = make_float2(v, __int_as_float(col));
        }
      }
    }
  }
  __syncthreads();

  if (tid < 256) {
    int c = lcnt[tid];
    const int grow = rowA0 + tid;
    if (c > SLOT) { flags[grow] = 1; c = SLOT; }
    if (c > 0) {
      const int base = atomicAdd(&cnt[grow], c);
      float2* dst = cand + (size_t)grow * CAND_CAP;
      for (int k = 0; k < c; ++k) {
        const int pos = base + k;
        if (pos < CAND_CAP) dst[pos] = lcand[tid * SLOT + k];
      }
      // if base+c > CAND_CAP, cnt[grow] ends > CAND_CAP -> topk flags the row
    }
  }
#undef DS_A
#undef DS_B
#undef MFMA_PH
#undef STAGE_A
#undef STAGE_B
#undef BAR
}

// ---------------- top-K from candidates + exact refinement + dense write ----
// One block (256 thr) per row.  If cnt in [32, CAP]: the row's h~ top-32 is
// provably inside the candidate list (all non-candidates < TAU <= Tm).
// 2-level radix (bits[30:20], [19:9]) -> 32nd-largest bucket [Tlo,Thi)
// (width ~6e-5).  v > Thi+D definite-in; [Tlo-D, Thi+D] refined exactly via
// f64 dot; else provably out.  Violated invariants -> flags -> fallback.
__global__ __launch_bounds__(256) void topk_cand_kernel(
    const float2* __restrict__ cand, const int* __restrict__ cnt,
    int* __restrict__ flags,
    float* __restrict__ latent,
    float* __restrict__ cvals, int* __restrict__ cidx,
    const float* __restrict__ X, const float* __restrict__ WT,
    const float* __restrict__ bias) {
  __shared__ float    sval[CAND_CAP];
  __shared__ int      sidx[CAND_CAP];
  __shared__ uint32_t hist[2048];
  __shared__ uint32_t chunkS[256];
  __shared__ float    swval[WCAP];
  __shared__ int      swidx[WCAP];
  __shared__ double   wexact[WCAP];
  __shared__ float    sel_val[K_TOP];
  __shared__ int      sel_idx[K_TOP];
  __shared__ uint32_t s_d, s_ab;
  __shared__ int      s_ndef, s_nw, s_bad;

  const int tid = threadIdx.x;
  const int row = blockIdx.x;
  const int n = cnt[row];

  if (n < K_TOP || n > CAND_CAP) {
    if (tid == 0) flags[row] = 1;
    return;
  }

  const float2* crow = cand + (size_t)row * CAND_CAP;
  for (int i = tid; i < n; i += 256) {
    const float2 c = crow[i];
    sval[i] = c.x;
    sidx[i] = __float_as_int(c.y);
  }
  __syncthreads();

  // ---- 2-level radix on candidate f32 bits (all values >= TAU > 0) ----
  uint32_t prefTop = 0, d1 = 0, needL = K_TOP;
#pragma unroll 1
  for (int level = 0; level < 2; ++level) {
    const int shift = level ? 9 : 20;
    for (int b = tid; b < 2048; b += 256) hist[b] = 0;
    __syncthreads();
    for (int i = tid; i < n; i += 256) {
      const uint32_t k = __float_as_uint(sval[i]);
      if (level == 0 || (k >> 20) == prefTop)
        atomicAdd(&hist[(k >> shift) & 2047], 1u);
    }
    __syncthreads();
    uint32_t cs = 0;
#pragma unroll
    for (int c = 0; c < 8; ++c) cs += hist[tid * 8 + c];
    chunkS[tid] = cs;
    __syncthreads();
    for (int off = 1; off < 256; off <<= 1) {
      const uint32_t v = (tid + off < 256) ? chunkS[tid + off] : 0u;
      __syncthreads();
      chunkS[tid] += v;
      __syncthreads();
    }
    {
      uint32_t cum = (tid + 1 < 256) ? chunkS[tid + 1] : 0u;
#pragma unroll
      for (int c = 7; c >= 0; --c) {
        const int bb = tid * 8 + c;
        const uint32_t nxt = cum;
        cum += hist[bb];
        if (cum >= needL && nxt < needL) { s_d = (uint32_t)bb; s_ab = nxt; }
      }
    }
    __syncthreads();
    if (level == 0) { prefTop = s_d; needL = needL - s_ab; }
    else            { d1 = s_d; }
    __syncthreads();
  }

  const uint32_t blo_bits = (prefTop << 20) | (d1 << 9);
  const float Tlo = __uint_as_float(blo_bits);
  const float Thi = __uint_as_float(blo_bits + 512u);
  const float Tp = Thi + TK_DELTA;
  const float Tm = Tlo - TK_DELTA;

  if (Tm < TAU) {   // window extends below candidate floor (never expected)
    if (tid == 0) flags[row] = 1;
    return;
  }

  // ---- classify candidates: definite-in / window ----
  if (tid == 0) { s_ndef = 0; s_nw = 0; s_bad = 0; }
  __syncthreads();
  for (int i = tid; i < n; i += 256) {
    const float v = sval[i];
    if (v > Tp) {
      const int pos = atomicAdd(&s_ndef, 1);
      if (pos < K_TOP) {
        cvals[(size_t)row * K_TOP + pos] = v;
        cidx[(size_t)row * K_TOP + pos]  = sidx[i];
        sel_val[pos] = v;
        sel_idx[pos] = sidx[i];
      } else {
        s_bad = 1;
      }
    } else if (v >= Tm) {
      const int pos = atomicAdd(&s_nw, 1);
      if (pos < WCAP) { swval[pos] = v; swidx[pos] = sidx[i]; }
      else            { s_bad = 1; }
    }
  }
  __syncthreads();
  const int ndef = s_ndef;
  const int nw   = s_nw;
  if (s_bad || ndef >= K_TOP) {
    if (tid == 0) flags[row] = 1;
    return;
  }
  const int r = K_TOP - ndef;     // >= 1

  // ---- exact f64 refinement of window members ----
  {
    const int wv = tid >> 6, ln = tid & 63;
    const float* xr = X + (size_t)row * D_IN;
    for (int c = wv; c < nw; c += 4) {
      const float* wrp = WT + (size_t)swidx[c] * D_IN;
      double a = 0.0;
#pragma unroll
      for (int j = 0; j < 16; ++j)
        a += (double)xr[ln + 64 * j] * (double)wrp[ln + 64 * j];
#pragma unroll
      for (int off = 32; off; off >>= 1) a += __shfl_xor(a, off);
      if (ln == 0) wexact[c] = a + (double)bias[swidx[c]];
    }
  }
  __syncthreads();
  // rank window by (exact desc, index asc) = jax tie-break; take top r
  if (tid < nw) {
    const double ei = wexact[tid];
    const int    ii = swidx[tid];
    int rank = 0;
    for (int j = 0; j < nw; ++j) {
      const double ej = wexact[j];
      const int    ij = swidx[j];
      rank += (ej > ei) || (ej == ei && ij < ii);
    }
    if (rank < r) {
      cvals[(size_t)row * K_TOP + ndef + rank] = swval[tid];
      cidx[(size_t)row * K_TOP + ndef + rank]  = ii;
      sel_val[ndef + rank] = swval[tid];
      sel_idx[ndef + rank] = ii;
    }
  }
  __syncthreads();

  // ---- dense latent row: zeros + 32 selected ----
  float* rowp = latent + (size_t)row * H_HID;
  const float4 z4 = make_float4(0.f, 0.f, 0.f, 0.f);
  for (int i4 = tid; i4 < H_HID / 4; i4 += 256)
    reinterpret_cast<float4*>(rowp)[i4] = z4;
  __syncthreads();
  if (tid < K_TOP) rowp[sel_idx[tid]] = sel_val[tid];
}

// ---------------- exact fallback (expected-never path) ----------------
// One block PER ROW; immediate exit when flag==0 (the R7 version was a single
// serial block scanning 4096 flags -> ~300-450us of pure latency per call).
// Flagged rows: exact f64 row in 128KB dynamic LDS, top-32 by
// (value desc, idx asc), write latent row + cvals/cidx.  Bit-exact.
__global__ __launch_bounds__(256) void fallback_kernel(
    const int* __restrict__ flags,
    const float* __restrict__ X, const float* __restrict__ WT,
    const float* __restrict__ bias,
    float* __restrict__ latent, float* __restrict__ cvals,
    int* __restrict__ cidx) {
  extern __shared__ double sc[];   // [H_HID] doubles = 128 KB dynamic
  __shared__ double rb[256];
  __shared__ int    ri[256];
  const int row = blockIdx.x;
  if (flags[row] == 0) return;
  const int tid = threadIdx.x;
  const float* xr = X + (size_t)row * D_IN;
  for (int c = tid; c < H_HID; c += 256) {
    const float* wrp = WT + (size_t)c * D_IN;
    double a = (double)bias[c];
    for (int j = 0; j < D_IN; ++j)
      a += (double)xr[j] * (double)wrp[j];
    sc[c] = fmax(a, 0.0);   // relu
  }
  float* rowp = latent + (size_t)row * H_HID;
  for (int i = tid; i < H_HID; i += 256) rowp[i] = 0.0f;
  __syncthreads();
#pragma unroll 1
  for (int k = 0; k < K_TOP; ++k) {
    double bv = -1.0; int bi = H_HID;
    for (int c = tid; c < H_HID; c += 256) {
      const double v = sc[c];
      if (v > bv || (v == bv && c < bi)) { bv = v; bi = c; }
    }
    rb[tid] = bv; ri[tid] = bi;
    __syncthreads();
    for (int off = 128; off; off >>= 1) {
      if (tid < off) {
        if (rb[tid + off] > rb[tid] ||
            (rb[tid + off] == rb[tid] && ri[tid + off] < ri[tid])) {
          rb[tid] = rb[tid + off]; ri[tid] = ri[tid + off];
        }
      }
      __syncthreads();
    }
    if (tid == 0) {
      const int ii = ri[0];
      const float vv = (float)rb[0];
      cvals[(size_t)row * K_TOP + k] = vv;
      cidx[(size_t)row * K_TOP + k]  = ii;
      rowp[ii] = vv;
      sc[ii] = -1.0;
    }
    __syncthreads();
  }
}

// ---------------- sparse decoder ----------------
__global__ __launch_bounds__(256) void decode_kernel(const float* __restrict__ cvals,
                                                     const int* __restrict__ cidx,
                                                     const float* __restrict__ Wdec,
                                                     const float* __restrict__ bias,
                                                     float* __restrict__ recon) {
  __shared__ float sv[K_TOP];
  __shared__ int   si[K_TOP];
  const int tid = threadIdx.x;
  const int row = blockIdx.x;
  if (tid < K_TOP) {
    sv[tid] = cvals[row * K_TOP + tid];
    si[tid] = cidx[row * K_TOP + tid];
  }
  __syncthreads();
  const float4 b4 = reinterpret_cast<const float4*>(bias)[tid];
  float ax = b4.x, ay = b4.y, az = b4.z, aw = b4.w;
#pragma unroll 1
  for (int k = 0; k < K_TOP; ++k) {
    const float v = sv[k];
    const float4 w = reinterpret_cast<const float4*>(Wdec + (size_t)si[k] * D_IN)[tid];
    ax = fmaf(v, w.x, ax);
    ay = fmaf(v, w.y, ay);
    az = fmaf(v, w.z, az);
    aw = fmaf(v, w.w, aw);
  }
  reinterpret_cast<float4*>(recon + (size_t)row * D_IN)[tid] = make_float4(ax, ay, az, aw);
}

// ---------------- launch ----------------

extern "C" void kernel_launch(void* const* d_in, const int* in_sizes, int n_in,
                              void* d_out, int out_size, void* d_ws, size_t ws_size,
                              hipStream_t stream) {
  (void)in_sizes; (void)n_in; (void)out_size; (void)ws_size;
  const float* Xv     = (const float*)d_in[0];
  const float* Xt     = (const float*)d_in[1];
  const float* Wv_enc = (const float*)d_in[2];
  const float* bv_enc = (const float*)d_in[3];
  const float* Wt_enc = (const float*)d_in[4];
  const float* bt_enc = (const float*)d_in[5];
  const float* Wv_dec = (const float*)d_in[6];
  const float* bv_dec = (const float*)d_in[7];
  const float* Wt_dec = (const float*)d_in[8];
  const float* bt_dec = (const float*)d_in[9];

  float* out      = (float*)d_out;
  float* recon_v  = out;
  float* recon_t  = out + (size_t)B_ROWS * D_IN;
  float* latent_v = out + 2ull * B_ROWS * D_IN;
  float* latent_t = latent_v + (size_t)B_ROWS * H_HID;

  char* ws = (char*)d_ws;
  const size_t szA = (size_t)B_ROWS * D_IN;    // 4M elems
  const size_t szB = (size_t)H_HID * D_IN;     // 16M elems
  const size_t szC = (size_t)B_ROWS * CAND_CAP;
  ushort* Ah_v  = (ushort*)ws;
  ushort* Ah_t  = Ah_v + szA;
  ushort* Bh_v  = Ah_t + szA;
  ushort* Bh_t  = Bh_v + szB;
  float*  WT32_v = (float*)(Bh_t + szB);
  float*  WT32_t = WT32_v + szB;
  float2* cand_v = (float2*)(WT32_t + szB);
  float2* cand_t = cand_v + szC;
  int*    cnt_v   = (int*)(cand_t + szC);
  int*    cnt_t   = cnt_v + B_ROWS;
  int*    flags_v = cnt_t + B_ROWS;
  int*    flags_t = flags_v + B_ROWS;
  float*  cvals_v = (float*)(flags_t + B_ROWS);
  float*  cvals_t = cvals_v + (size_t)B_ROWS * K_TOP;
  int*    cidx_v  = (int*)(cvals_t + (size_t)B_ROWS * K_TOP);
  int*    cidx_t  = cidx_v + (size_t)B_ROWS * K_TOP;

  hipFuncSetAttribute((const void*)gemm_enc_8ph,
                      hipFuncAttributeMaxDynamicSharedMemorySize, 131072);
  hipFuncSetAttribute((const void*)fallback_kernel,
                      hipFuncAttributeMaxDynamicSharedMemorySize, 131072);

  // zero counters + flags (contiguous 64 KB)
  hipMemsetAsync(cnt_v, 0, 4 * B_ROWS * sizeof(int), stream);

  // splits
  split_a_kernel<<<B_ROWS * D_IN / 1024, 256, 0, stream>>>(Xv, Ah_v);
  split_a_kernel<<<B_ROWS * D_IN / 1024, 256, 0, stream>>>(Xt, Ah_t);
  dim3 tg(H_HID / 32, D_IN / 32);
  split_wt_kernel<<<tg, dim3(32, 8), 0, stream>>>(Wv_enc, Bh_v, WT32_v);
  split_wt_kernel<<<tg, dim3(32, 8), 0, stream>>>(Wt_enc, Bh_t, WT32_t);

  // vision stream
  gemm_enc_8ph<<<(B_ROWS / 256) * (H_HID / 256), 512, 131072, stream>>>(
      Ah_v, Bh_v, bv_enc, cand_v, cnt_v, flags_v);
  topk_cand_kernel<<<B_ROWS, 256, 0, stream>>>(cand_v, cnt_v, flags_v, latent_v,
                                               cvals_v, cidx_v, Xv, WT32_v, bv_enc);
  fallback_kernel<<<B_ROWS, 256, 131072, stream>>>(flags_v, Xv, WT32_v, bv_enc,
                                                   latent_v, cvals_v, cidx_v);
  decode_kernel<<<B_ROWS, 256, 0, stream>>>(cvals_v, cidx_v, Wv_dec, bv_dec, recon_v);

  // text stream
  gemm_enc_8ph<<<(B_ROWS / 256) * (H_HID / 256), 512, 131072, stream>>>(
      Ah_t, Bh_t, bt_enc, cand_t, cnt_t, flags_t);
  topk_cand_kernel<<<B_ROWS, 256, 0, stream>>>(cand_t, cnt_t, flags_t, latent_t,
                                               cvals_t, cidx_t, Xt, WT32_t, bt_enc);
  fallback_kernel<<<B_ROWS, 256, 131072, stream>>>(flags_t, Xt, WT32_t, bt_enc,
                                                   latent_t, cvals_t, cidx_t);
  decode_kernel<<<B_ROWS, 256, 0, stream>>>(cvals_t, cidx_t, Wt_dec, bt_dec, recon_t);
}

// Round 10
// 693.014 us; speedup vs baseline: 2.9938x; 1.0632x over previous
//
#include <hip/hip_runtime.h>
#include <hip/hip_fp16.h>
#include <stdint.h>

#define B_ROWS 4096
#define D_IN   1024
#define H_HID  16384
#define K_TOP  32

#define CAND_CAP 1536     // per-row candidate capacity (mean 682, sigma 26)
#define SLOT     32       // per-(row, 256-col block) LDS slots (mean 10.7, sigma 3.3)
#define TAU      1.0f     // fixed candidate threshold; safety via flags+fallback
#define TK_DELTA 1e-2f    // refinement window half-width (>= 2x 12-sigma h~ error)
#define WCAP     256

typedef __attribute__((ext_vector_type(8))) _Float16 half8;
typedef __attribute__((ext_vector_type(4))) float    f32x4;

// ---------------- helpers ----------------

// f16 hi part; zero if |x| below f16 min-normal (deterministic error bound).
__device__ __forceinline__ ushort hi16(float x) {
  return (fabsf(x) >= 0x1p-14f) ? __half_as_ushort(__float2half(x)) : (ushort)0;
}

__device__ __forceinline__ void gload_lds16(const void* g, void* l) {
  __builtin_amdgcn_global_load_lds(
      (const __attribute__((address_space(1))) void*)g,
      (__attribute__((address_space(3))) void*)l, 16, 0, 0);
}

// ---------------- split kernels (both streams in one dispatch) ----------------

__global__ __launch_bounds__(256) void split_a_kernel(const float* __restrict__ x0,
                                                      const float* __restrict__ x1,
                                                      ushort* __restrict__ hi0,
                                                      ushort* __restrict__ hi1) {
  const int nb = B_ROWS * D_IN / 1024;          // blocks per stream
  const int s = blockIdx.x >= nb;
  const float* x = s ? x1 : x0;
  ushort* hi = s ? hi1 : hi0;
  const int t = (blockIdx.x - s * nb) * 256 + threadIdx.x;
  const int base = t * 4;
  float4 v = *reinterpret_cast<const float4*>(x + base);
  ushort4 h;
  h.x = hi16(v.x); h.y = hi16(v.y); h.z = hi16(v.z); h.w = hi16(v.w);
  *reinterpret_cast<ushort4*>(hi + base) = h;
}

// W [D_IN, H_HID] f32 -> hiT [H_HID, D_IN] f16 bits + wT32 [H_HID, D_IN] f32
__global__ __launch_bounds__(256) void split_wt_kernel(const float* __restrict__ W0,
                                                       const float* __restrict__ W1,
                                                       ushort* __restrict__ hiT0,
                                                       ushort* __restrict__ hiT1,
                                                       float* __restrict__ wT0,
                                                       float* __restrict__ wT1) {
  __shared__ float tile[32][33];
  const int s = blockIdx.z;
  const float* W = s ? W1 : W0;
  ushort* hiT = s ? hiT1 : hiT0;
  float*  wT32 = s ? wT1 : wT0;
  const int c0 = blockIdx.x * 32;
  const int r0 = blockIdx.y * 32;
  const int tx = threadIdx.x;
  const int ty = threadIdx.y;
#pragma unroll
  for (int i = 0; i < 32; i += 8)
    tile[ty + i][tx] = W[(size_t)(r0 + ty + i) * H_HID + c0 + tx];
  __syncthreads();
#pragma unroll
  for (int i = 0; i < 32; i += 8) {
    float v = tile[tx][ty + i];
    size_t o = (size_t)(c0 + ty + i) * D_IN + r0 + tx;
    hiT[o]  = hi16(v);
    wT32[o] = v;
  }
}

// ---------------- encoder GEMM: 256x256 tile, 8-phase pipelined ----------------
// Both streams in one 2048-block dispatch.  h~ = Ah @ Bh^T + b; v >= TAU
// candidates LDS-aggregated then one bulk atomicAdd per row per block.
#define NTILES 16   // 1024 / 64

__global__ __launch_bounds__(512, 2) void gemm_enc_8ph(const ushort* __restrict__ Ah0,
                                                       const ushort* __restrict__ Ah1,
                                                       const ushort* __restrict__ Bh0,
                                                       const ushort* __restrict__ Bh1,
                                                       const float* __restrict__ bias0,
                                                       const float* __restrict__ bias1,
                                                       float2* __restrict__ cand,
                                                       int* __restrict__ cnt,
                                                       int* __restrict__ flags) {
  extern __shared__ ushort smem[];   // [2][32768]: buf*32768, B-half at +16384
  const int tid  = threadIdx.x;
  const int wid  = tid >> 6;
  const int lane = tid & 63;
  const int wr   = wid >> 2;
  const int wc   = wid & 3;
  const int strm = blockIdx.x >> 10;            // 0: vision, 1: text
  const int bid  = blockIdx.x & 1023;
  const ushort* Ah = strm ? Ah1 : Ah0;
  const ushort* Bh = strm ? Bh1 : Bh0;
  const float* bias = strm ? bias1 : bias0;
  const int tm   = bid & 15;
  const int tn   = bid >> 4;
  const int rowA0 = tm * 256;
  const int rowB0 = tn * 256;

  const int st_row = wid * 8 + (lane >> 3);
  const int st_lin = lane & 7;
  const int st_src = (lane & 7) ^ ((lane >> 3) & 7);
  const int fr   = lane & 15;
  const int fk   = lane >> 4;
  const int swz8 = (lane & 7) << 3;

  f32x4 acc[8][4];
#pragma unroll
  for (int i = 0; i < 8; ++i)
#pragma unroll
    for (int j = 0; j < 4; ++j) {
      f32x4 z = {0.f, 0.f, 0.f, 0.f};
      acc[i][j] = z;
    }
  half8 a[4][2], b[4][2];

#define DS_A(MH)                                                            \
  _Pragma("unroll") for (int m = 0; m < 4; ++m)                             \
  _Pragma("unroll") for (int k = 0; k < 2; ++k) {                           \
    const int r = wr * 128 + ((MH) * 4 + m) * 16 + fr;                      \
    const int idx = (r * 64 + k * 32 + fk * 8) ^ swz8;                      \
    a[m][k] = *reinterpret_cast<const half8*>(Acur + idx);                  \
  }
#define DS_B(NH)                                                            \
  _Pragma("unroll") for (int n = 0; n < 2; ++n)                             \
  _Pragma("unroll") for (int k = 0; k < 2; ++k) {                           \
    const int r = wc * 64 + ((NH) * 2 + n) * 16 + fr;                       \
    const int idx = (r * 64 + k * 32 + fk * 8) ^ swz8;                      \
    b[(NH) * 2 + n][k] = *reinterpret_cast<const half8*>(Bcur + idx);       \
  }
#define MFMA_PH(MH, NH)                                                     \
  __builtin_amdgcn_s_setprio(1);                                            \
  _Pragma("unroll") for (int m = 0; m < 4; ++m)                             \
  _Pragma("unroll") for (int n = 0; n < 2; ++n)                             \
  _Pragma("unroll") for (int k = 0; k < 2; ++k)                             \
    acc[(MH) * 4 + m][(NH) * 2 + n] = __builtin_amdgcn_mfma_f32_16x16x32_f16( \
        a[m][k], b[(NH) * 2 + n][k], acc[(MH) * 4 + m][(NH) * 2 + n], 0, 0, 0); \
  __builtin_amdgcn_s_setprio(0);
#define STAGE_A(Q)                                                          \
  gload_lds16(Ah + (size_t)(rowA0 + (Q) * 64 + st_row) * 1024 + k0 + st_src * 8, \
              Lnxt + ((Q) * 64 + st_row) * 64 + st_lin * 8)
#define STAGE_B(Q)                                                          \
  gload_lds16(Bh + (size_t)(rowB0 + (Q) * 64 + st_row) * 1024 + k0 + st_src * 8, \
              Lnxt + 16384 + ((Q) * 64 + st_row) * 64 + st_lin * 8)
#define BAR() __builtin_amdgcn_s_barrier()

  // prologue: stage tile 0 into buf0.  Order: Bq0..3, Aq0, Aq2, Aq1, Aq3.
  int k0 = 0;
  ushort* Lnxt = smem;
  STAGE_B(0); STAGE_B(1); STAGE_B(2); STAGE_B(3);
  STAGE_A(0); STAGE_A(2); STAGE_A(1); STAGE_A(3);
  asm volatile("s_waitcnt vmcnt(2)" ::: "memory");
  BAR();

#pragma unroll 1
  for (int t = 0; t < NTILES - 1; ++t) {
    const int cur = t & 1;
    const ushort* Acur = smem + cur * 32768;
    const ushort* Bcur = Acur + 16384;
    Lnxt = smem + (cur ^ 1) * 32768;
    k0 = (t + 1) << 6;

    // phase 1
    DS_A(0); DS_B(0);
    STAGE_B(0); STAGE_B(1);
    BAR();
    MFMA_PH(0, 0);
    BAR();
    // phase 2
    DS_B(1);
    STAGE_B(2); STAGE_B(3);
    BAR();
    MFMA_PH(0, 1);
    asm volatile("s_waitcnt vmcnt(4)" ::: "memory");
    BAR();
    // phase 3
    DS_A(1);
    STAGE_A(0); STAGE_A(2);
    BAR();
    MFMA_PH(1, 0);
    BAR();
    // phase 4
    STAGE_A(1); STAGE_A(3);
    BAR();
    MFMA_PH(1, 1);
    asm volatile("s_waitcnt vmcnt(2)" ::: "memory");
    BAR();
  }

  // epilogue tile (no staging)
  {
    const ushort* Acur = smem + ((NTILES - 1) & 1) * 32768;
    const ushort* Bcur = Acur + 16384;
    DS_A(0); DS_B(0);
    BAR();
    MFMA_PH(0, 0);
    BAR();
    DS_B(1);
    BAR();
    MFMA_PH(0, 1);
    asm volatile("s_waitcnt vmcnt(0)" ::: "memory");
    BAR();
    DS_A(1);
    BAR();
    MFMA_PH(1, 0);
    BAR();
    MFMA_PH(1, 1);
  }

  // ---- epilogue: LDS-aggregated candidate push (reuse dead smem) ----
  char* sb = reinterpret_cast<char*>(smem);
  int*    lcnt  = reinterpret_cast<int*>(sb);            // [256]
  float2* lcand = reinterpret_cast<float2*>(sb + 1024);  // [256][SLOT] = 64 KB

  __syncthreads();
  if (tid < 256) lcnt[tid] = 0;
  __syncthreads();

  const int ccol = lane & 15;
  const int crow = (lane >> 4) * 4;
#pragma unroll
  for (int j = 0; j < 4; ++j) {
    const int col = tn * 256 + wc * 64 + j * 16 + ccol;
    const float bv = bias[col];
#pragma unroll
    for (int i = 0; i < 8; ++i) {
      const int lrow0 = wr * 128 + i * 16 + crow;
#pragma unroll
      for (int p = 0; p < 4; ++p) {
        const float v = acc[i][j][p] + bv;
        if (v >= TAU) {
          const int lrow = lrow0 + p;
          const int pos = atomicAdd(&lcnt[lrow], 1);
          if (pos < SLOT)
            lcand[lrow * SLOT + pos] = make_float2(v, __int_as_float(col));
        }
      }
    }
  }
  __syncthreads();

  if (tid < 256) {
    int c = lcnt[tid];
    const int grow = strm * B_ROWS + rowA0 + tid;   // global row id (both streams)
    if (c > SLOT) { flags[grow] = 1; c = SLOT; }
    if (c > 0) {
      const int base = atomicAdd(&cnt[grow], c);
      float2* dst = cand + (size_t)grow * CAND_CAP;
      for (int k = 0; k < c; ++k) {
        const int pos = base + k;
        if (pos < CAND_CAP) dst[pos] = lcand[tid * SLOT + k];
      }
      // if base+c > CAND_CAP, cnt[grow] ends > CAND_CAP -> topk flags the row
    }
  }
#undef DS_A
#undef DS_B
#undef MFMA_PH
#undef STAGE_A
#undef STAGE_B
#undef BAR
}

// ---------------- top-K from candidates + refinement + latent + DECODE -------
// One block (256 thr) per (stream, row) = 8192 blocks.  Select exact top-32
// (radix -> window -> exact f64 refinement, jax tie-break), write dense latent
// (zeros + 32), then compute recon = b_dec + sum val*Wdec[idx] directly from
// the in-LDS selection (decode fused; no cvals/cidx round trip).
__global__ __launch_bounds__(256) void topk_decode_kernel(
    const float2* __restrict__ cand, const int* __restrict__ cnt,
    int* __restrict__ flags,
    float* __restrict__ latent0, float* __restrict__ latent1,
    float* __restrict__ recon0, float* __restrict__ recon1,
    const float* __restrict__ X0, const float* __restrict__ X1,
    const float* __restrict__ WT0, const float* __restrict__ WT1,
    const float* __restrict__ be0, const float* __restrict__ be1,
    const float* __restrict__ Wd0, const float* __restrict__ Wd1,
    const float* __restrict__ bd0, const float* __restrict__ bd1) {
  __shared__ float    sval[CAND_CAP];
  __shared__ int      sidx[CAND_CAP];
  __shared__ uint32_t hist[2048];
  __shared__ uint32_t chunkS[256];
  __shared__ float    swval[WCAP];
  __shared__ int      swidx[WCAP];
  __shared__ double   wexact[WCAP];
  __shared__ float    sel_val[K_TOP];
  __shared__ int      sel_idx[K_TOP];
  __shared__ uint32_t s_d, s_ab;
  __shared__ int      s_ndef, s_nw, s_bad;

  const int tid  = threadIdx.x;
  const int grow = blockIdx.x;            // global row (stream-merged)
  const int strm = grow >> 12;
  const int row  = grow & (B_ROWS - 1);
  const int n = cnt[grow];

  float* latent = strm ? latent1 : latent0;
  float* recon  = strm ? recon1 : recon0;
  const float* X    = strm ? X1 : X0;
  const float* WT   = strm ? WT1 : WT0;
  const float* benc = strm ? be1 : be0;
  const float* Wdec = strm ? Wd1 : Wd0;
  const float* bdec = strm ? bd1 : bd0;

  if (n < K_TOP || n > CAND_CAP) {
    if (tid == 0) flags[grow] = 1;
    return;
  }

  const float2* crow = cand + (size_t)grow * CAND_CAP;
  for (int i = tid; i < n; i += 256) {
    const float2 c = crow[i];
    sval[i] = c.x;
    sidx[i] = __float_as_int(c.y);
  }
  __syncthreads();

  // ---- 2-level radix on candidate f32 bits (all values >= TAU > 0) ----
  uint32_t prefTop = 0, d1 = 0, needL = K_TOP;
#pragma unroll 1
  for (int level = 0; level < 2; ++level) {
    const int shift = level ? 9 : 20;
    for (int b = tid; b < 2048; b += 256) hist[b] = 0;
    __syncthreads();
    for (int i = tid; i < n; i += 256) {
      const uint32_t k = __float_as_uint(sval[i]);
      if (level == 0 || (k >> 20) == prefTop)
        atomicAdd(&hist[(k >> shift) & 2047], 1u);
    }
    __syncthreads();
    uint32_t cs = 0;
#pragma unroll
    for (int c = 0; c < 8; ++c) cs += hist[tid * 8 + c];
    chunkS[tid] = cs;
    __syncthreads();
    for (int off = 1; off < 256; off <<= 1) {
      const uint32_t v = (tid + off < 256) ? chunkS[tid + off] : 0u;
      __syncthreads();
      chunkS[tid] += v;
      __syncthreads();
    }
    {
      uint32_t cum = (tid + 1 < 256) ? chunkS[tid + 1] : 0u;
#pragma unroll
      for (int c = 7; c >= 0; --c) {
        const int bb = tid * 8 + c;
        const uint32_t nxt = cum;
        cum += hist[bb];
        if (cum >= needL && nxt < needL) { s_d = (uint32_t)bb; s_ab = nxt; }
      }
    }
    __syncthreads();
    if (level == 0) { prefTop = s_d; needL = needL - s_ab; }
    else            { d1 = s_d; }
    __syncthreads();
  }

  const uint32_t blo_bits = (prefTop << 20) | (d1 << 9);
  const float Tlo = __uint_as_float(blo_bits);
  const float Thi = __uint_as_float(blo_bits + 512u);
  const float Tp = Thi + TK_DELTA;
  const float Tm = Tlo - TK_DELTA;

  if (Tm < TAU) {   // window extends below candidate floor (never expected)
    if (tid == 0) flags[grow] = 1;
    return;
  }

  // ---- classify candidates: definite-in / window ----
  if (tid == 0) { s_ndef = 0; s_nw = 0; s_bad = 0; }
  __syncthreads();
  for (int i = tid; i < n; i += 256) {
    const float v = sval[i];
    if (v > Tp) {
      const int pos = atomicAdd(&s_ndef, 1);
      if (pos < K_TOP) { sel_val[pos] = v; sel_idx[pos] = sidx[i]; }
      else             { s_bad = 1; }
    } else if (v >= Tm) {
      const int pos = atomicAdd(&s_nw, 1);
      if (pos < WCAP) { swval[pos] = v; swidx[pos] = sidx[i]; }
      else            { s_bad = 1; }
    }
  }
  __syncthreads();
  const int ndef = s_ndef;
  const int nw   = s_nw;
  if (s_bad || ndef >= K_TOP) {
    if (tid == 0) flags[grow] = 1;
    return;
  }
  const int r = K_TOP - ndef;     // >= 1

  // ---- exact f64 refinement of window members ----
  {
    const int wv = tid >> 6, ln = tid & 63;
    const float* xr = X + (size_t)row * D_IN;
    for (int c = wv; c < nw; c += 4) {
      const float* wrp = WT + (size_t)swidx[c] * D_IN;
      double a = 0.0;
#pragma unroll
      for (int j = 0; j < 16; ++j)
        a += (double)xr[ln + 64 * j] * (double)wrp[ln + 64 * j];
#pragma unroll
      for (int off = 32; off; off >>= 1) a += __shfl_xor(a, off);
      if (ln == 0) wexact[c] = a + (double)benc[swidx[c]];
    }
  }
  __syncthreads();
  // rank window by (exact desc, index asc) = jax tie-break; take top r
  if (tid < nw) {
    const double ei = wexact[tid];
    const int    ii = swidx[tid];
    int rank = 0;
    for (int j = 0; j < nw; ++j) {
      const double ej = wexact[j];
      const int    ij = swidx[j];
      rank += (ej > ei) || (ej == ei && ij < ii);
    }
    if (rank < r) { sel_val[ndef + rank] = swval[tid]; sel_idx[ndef + rank] = ii; }
  }
  __syncthreads();

  // ---- dense latent row: zeros + 32 selected ----
  float* rowp = latent + (size_t)row * H_HID;
  const float4 z4 = make_float4(0.f, 0.f, 0.f, 0.f);
  for (int i4 = tid; i4 < H_HID / 4; i4 += 256)
    reinterpret_cast<float4*>(rowp)[i4] = z4;
  __syncthreads();   // zeros complete BEFORE scatter (R9 bug: missing barrier)
  if (tid < K_TOP) rowp[sel_idx[tid]] = sel_val[tid];

  // ---- fused decode: recon = b_dec + sum_k val_k * Wdec[idx_k, :] ----
  const float4 b4 = reinterpret_cast<const float4*>(bdec)[tid];
  float ax = b4.x, ay = b4.y, az = b4.z, aw = b4.w;
#pragma unroll 1
  for (int k = 0; k < K_TOP; ++k) {
    const float v = sel_val[k];
    const float4 w = reinterpret_cast<const float4*>(Wdec + (size_t)sel_idx[k] * D_IN)[tid];
    ax = fmaf(v, w.x, ax);
    ay = fmaf(v, w.y, ay);
    az = fmaf(v, w.z, az);
    aw = fmaf(v, w.w, aw);
  }
  reinterpret_cast<float4*>(recon + (size_t)row * D_IN)[tid] = make_float4(ax, ay, az, aw);
}

// ---------------- exact fallback (expected-never path) ----------------
// One block per (stream,row); immediate exit when flag==0.  Flagged rows:
// exact f64 row in 128KB dynamic LDS, top-32 by (value desc, idx asc), write
// latent row + recon.  Bit-exact.
__global__ __launch_bounds__(256) void fallback_kernel(
    const int* __restrict__ flags,
    const float* __restrict__ X0, const float* __restrict__ X1,
    const float* __restrict__ WT0, const float* __restrict__ WT1,
    const float* __restrict__ be0, const float* __restrict__ be1,
    float* __restrict__ latent0, float* __restrict__ latent1,
    float* __restrict__ recon0, float* __restrict__ recon1,
    const float* __restrict__ Wd0, const float* __restrict__ Wd1,
    const float* __restrict__ bd0, const float* __restrict__ bd1) {
  extern __shared__ double sc[];   // [H_HID] doubles = 128 KB dynamic
  __shared__ double rb[256];
  __shared__ int    ri[256];
  __shared__ float  fsel_val[K_TOP];
  __shared__ int    fsel_idx[K_TOP];
  const int grow = blockIdx.x;
  if (flags[grow] == 0) return;
  const int strm = grow >> 12;
  const int row  = grow & (B_ROWS - 1);
  const int tid = threadIdx.x;
  const float* X    = strm ? X1 : X0;
  const float* WT   = strm ? WT1 : WT0;
  const float* benc = strm ? be1 : be0;
  float* latent = strm ? latent1 : latent0;
  float* recon  = strm ? recon1 : recon0;
  const float* Wdec = strm ? Wd1 : Wd0;
  const float* bdec = strm ? bd1 : bd0;

  const float* xr = X + (size_t)row * D_IN;
  for (int c = tid; c < H_HID; c += 256) {
    const float* wrp = WT + (size_t)c * D_IN;
    double a = (double)benc[c];
    for (int j = 0; j < D_IN; ++j)
      a += (double)xr[j] * (double)wrp[j];
    sc[c] = fmax(a, 0.0);   // relu
  }
  float* rowp = latent + (size_t)row * H_HID;
  for (int i = tid; i < H_HID; i += 256) rowp[i] = 0.0f;
  __syncthreads();
#pragma unroll 1
  for (int k = 0; k < K_TOP; ++k) {
    double bv = -1.0; int bi = H_HID;
    for (int c = tid; c < H_HID; c += 256) {
      const double v = sc[c];
      if (v > bv || (v == bv && c < bi)) { bv = v; bi = c; }
    }
    rb[tid] = bv; ri[tid] = bi;
    __syncthreads();
    for (int off = 128; off; off >>= 1) {
      if (tid < off) {
        if (rb[tid + off] > rb[tid] ||
            (rb[tid + off] == rb[tid] && ri[tid + off] < ri[tid])) {
          rb[tid] = rb[tid + off]; ri[tid] = ri[tid + off];
        }
      }
      __syncthreads();
    }
    if (tid == 0) {
      const int ii = ri[0];
      const float vv = (float)rb[0];
      fsel_val[k] = vv; fsel_idx[k] = ii;
      rowp[ii] = vv;
      sc[ii] = -1.0;
    }
    __syncthreads();
  }
  // recon for this row
  const float4 b4 = reinterpret_cast<const float4*>(bdec)[tid];
  float ax = b4.x, ay = b4.y, az = b4.z, aw = b4.w;
#pragma unroll 1
  for (int k = 0; k < K_TOP; ++k) {
    const float v = fsel_val[k];
    const float4 w = reinterpret_cast<const float4*>(Wdec + (size_t)fsel_idx[k] * D_IN)[tid];
    ax = fmaf(v, w.x, ax);
    ay = fmaf(v, w.y, ay);
    az = fmaf(v, w.z, az);
    aw = fmaf(v, w.w, aw);
  }
  reinterpret_cast<float4*>(recon + (size_t)row * D_IN)[tid] = make_float4(ax, ay, az, aw);
}

// ---------------- launch ----------------

extern "C" void kernel_launch(void* const* d_in, const int* in_sizes, int n_in,
                              void* d_out, int out_size, void* d_ws, size_t ws_size,
                              hipStream_t stream) {
  (void)in_sizes; (void)n_in; (void)out_size; (void)ws_size;
  const float* Xv     = (const float*)d_in[0];
  const float* Xt     = (const float*)d_in[1];
  const float* Wv_enc = (const float*)d_in[2];
  const float* bv_enc = (const float*)d_in[3];
  const float* Wt_enc = (const float*)d_in[4];
  const float* bt_enc = (const float*)d_in[5];
  const float* Wv_dec = (const float*)d_in[6];
  const float* bv_dec = (const float*)d_in[7];
  const float* Wt_dec = (const float*)d_in[8];
  const float* bt_dec = (const float*)d_in[9];

  float* out      = (float*)d_out;
  float* recon_v  = out;
  float* recon_t  = out + (size_t)B_ROWS * D_IN;
  float* latent_v = out + 2ull * B_ROWS * D_IN;
  float* latent_t = latent_v + (size_t)B_ROWS * H_HID;

  char* ws = (char*)d_ws;
  const size_t szA = (size_t)B_ROWS * D_IN;    // 4M elems
  const size_t szB = (size_t)H_HID * D_IN;     // 16M elems
  const size_t szC = (size_t)B_ROWS * CAND_CAP;
  ushort* Ah_v  = (ushort*)ws;
  ushort* Ah_t  = Ah_v + szA;
  ushort* Bh_v  = Ah_t + szA;
  ushort* Bh_t  = Bh_v + szB;
  float*  WT32_v = (float*)(Bh_t + szB);
  float*  WT32_t = WT32_v + szB;
  float2* cand  = (float2*)(WT32_t + szB);     // [2*B_ROWS][CAND_CAP]
  int*    cnt   = (int*)(cand + 2 * szC);      // [2*B_ROWS]
  int*    flags = cnt + 2 * B_ROWS;            // [2*B_ROWS]

  hipFuncSetAttribute((const void*)gemm_enc_8ph,
                      hipFuncAttributeMaxDynamicSharedMemorySize, 131072);
  hipFuncSetAttribute((const void*)fallback_kernel,
                      hipFuncAttributeMaxDynamicSharedMemorySize, 131072);

  // zero counters + flags (contiguous 64 KB)
  hipMemsetAsync(cnt, 0, 4 * B_ROWS * sizeof(int), stream);

  // splits (both streams per dispatch)
  split_a_kernel<<<2 * (B_ROWS * D_IN / 1024), 256, 0, stream>>>(Xv, Xt, Ah_v, Ah_t);
  split_wt_kernel<<<dim3(H_HID / 32, D_IN / 32, 2), dim3(32, 8), 0, stream>>>(
      Wv_enc, Wt_enc, Bh_v, Bh_t, WT32_v, WT32_t);

  // encoder GEMMs (both streams, one dispatch)
  gemm_enc_8ph<<<2048, 512, 131072, stream>>>(Ah_v, Ah_t, Bh_v, Bh_t,
                                              bv_enc, bt_enc, cand, cnt, flags);

  // top-K + refinement + latent + fused decode (both streams)
  topk_decode_kernel<<<2 * B_ROWS, 256, 0, stream>>>(
      cand, cnt, flags, latent_v, latent_t, recon_v, recon_t,
      Xv, Xt, WT32_v, WT32_t, bv_enc, bt_enc,
      Wv_dec, Wt_dec, bv_dec, bt_dec);

  // exact fallback for flagged rows (expected none)
  fallback_kernel<<<2 * B_ROWS, 256, 131072, stream>>>(
      flags, Xv, Xt, WT32_v, WT32_t, bv_enc, bt_enc,
      latent_v, latent_t, recon_v, recon_t,
      Wv_dec, Wt_dec, bv_dec, bt_dec);
}

// Round 11
// 690.334 us; speedup vs baseline: 3.0054x; 1.0039x over previous
//
#include <hip/hip_runtime.h>
#include <hip/hip_fp16.h>
#include <stdint.h>

#define B_ROWS 4096
#define D_IN   1024
#define H_HID  16384
#define K_TOP  32

#define CAND_CAP 1536     // per-row candidate capacity (mean 682, sigma 26)
#define SLOT     32       // per-(row, 256-col block) LDS slots (mean 10.7, sigma 3.3)
#define TAU      1.0f     // fixed candidate threshold; safety via flags+fallback
#define TK_DELTA 1e-2f    // refinement window half-width (>= 2x 12-sigma h~ error)
#define WCAP     256

typedef __attribute__((ext_vector_type(8))) _Float16 half8;
typedef __attribute__((ext_vector_type(4))) float    f32x4;

// ---------------- helpers ----------------

// f16 hi part; zero if |x| below f16 min-normal (deterministic error bound).
__device__ __forceinline__ ushort hi16(float x) {
  return (fabsf(x) >= 0x1p-14f) ? __half_as_ushort(__float2half(x)) : (ushort)0;
}

__device__ __forceinline__ void gload_lds16(const void* g, void* l) {
  __builtin_amdgcn_global_load_lds(
      (const __attribute__((address_space(1))) void*)g,
      (__attribute__((address_space(3))) void*)l, 16, 0, 0);
}

// ---------------- split kernels (both streams in one dispatch) ----------------

__global__ __launch_bounds__(256) void split_a_kernel(const float* __restrict__ x0,
                                                      const float* __restrict__ x1,
                                                      ushort* __restrict__ hi0,
                                                      ushort* __restrict__ hi1) {
  const int nb = B_ROWS * D_IN / 1024;          // blocks per stream
  const int s = blockIdx.x >= nb;
  const float* x = s ? x1 : x0;
  ushort* hi = s ? hi1 : hi0;
  const int t = (blockIdx.x - s * nb) * 256 + threadIdx.x;
  const int base = t * 4;
  float4 v = *reinterpret_cast<const float4*>(x + base);
  ushort4 h;
  h.x = hi16(v.x); h.y = hi16(v.y); h.z = hi16(v.z); h.w = hi16(v.w);
  *reinterpret_cast<ushort4*>(hi + base) = h;
}

// W [D_IN, H_HID] f32 -> hiT [H_HID, D_IN] f16 bits + wT32 [H_HID, D_IN] f32
__global__ __launch_bounds__(256) void split_wt_kernel(const float* __restrict__ W0,
                                                       const float* __restrict__ W1,
                                                       ushort* __restrict__ hiT0,
                                                       ushort* __restrict__ hiT1,
                                                       float* __restrict__ wT0,
                                                       float* __restrict__ wT1) {
  __shared__ float tile[32][33];
  const int s = blockIdx.z;
  const float* W = s ? W1 : W0;
  ushort* hiT = s ? hiT1 : hiT0;
  float*  wT32 = s ? wT1 : wT0;
  const int c0 = blockIdx.x * 32;
  const int r0 = blockIdx.y * 32;
  const int tx = threadIdx.x;
  const int ty = threadIdx.y;
#pragma unroll
  for (int i = 0; i < 32; i += 8)
    tile[ty + i][tx] = W[(size_t)(r0 + ty + i) * H_HID + c0 + tx];
  __syncthreads();
#pragma unroll
  for (int i = 0; i < 32; i += 8) {
    float v = tile[tx][ty + i];
    size_t o = (size_t)(c0 + ty + i) * D_IN + r0 + tx;
    hiT[o]  = hi16(v);
    wT32[o] = v;
  }
}

// ---------------- encoder GEMM: 256x256 tile, 16 waves, 2-phase/K-tile -------
// Both streams in one 2048-block dispatch.  16 waves (4Mx4N, 64x64 each) give
// 4 waves/SIMD (vs 2 with the 8-wave variant) -> MFMA pipe saturation.
// Per K-tile (BK=64): ph1 {ds k=0, stage all 4 x 16KB, bar, 16 MFMA, bar},
// ph2 {ds k=1, bar, 16 MFMA, vmcnt(0), bar}.  LDS layout, XOR swizzle and
// stage addressing identical to the proven 8-wave kernel.
#define NTILES 16   // 1024 / 64

__global__ __launch_bounds__(1024, 4) void gemm_enc_2ph(const ushort* __restrict__ Ah0,
                                                        const ushort* __restrict__ Ah1,
                                                        const ushort* __restrict__ Bh0,
                                                        const ushort* __restrict__ Bh1,
                                                        const float* __restrict__ bias0,
                                                        const float* __restrict__ bias1,
                                                        float2* __restrict__ cand,
                                                        int* __restrict__ cnt,
                                                        int* __restrict__ flags) {
  extern __shared__ ushort smem[];   // [2][32768]: buf*32768, B-half at +16384
  const int tid  = threadIdx.x;
  const int wid  = tid >> 6;
  const int lane = tid & 63;
  const int wr   = wid >> 2;          // 0..3 (M quarter: 64 rows)
  const int wc   = wid & 3;           // 0..3 (N quarter: 64 cols)
  const int strm = blockIdx.x >> 10;  // 0: vision, 1: text
  const int bid  = blockIdx.x & 1023;
  const ushort* Ah = strm ? Ah1 : Ah0;
  const ushort* Bh = strm ? Bh1 : Bh0;
  const float* bias = strm ? bias1 : bias0;
  const int tm   = bid & 15;
  const int tn   = bid >> 4;
  const int rowA0 = tm * 256;
  const int rowB0 = tn * 256;

  // staging: 1024 thr x 16B = 16KB per stage; A tile 32KB = 2 stages (128 rows)
  const int st_row  = tid >> 3;                 // 0..127
  const int st_unit = tid & 7;                  // linear 16B unit in row
  const int st_src  = st_unit ^ (st_row & 7);   // inverse-swizzled global unit
  // fragment geometry
  const int fr   = lane & 15;
  const int fk   = lane >> 4;                   // 0..3
  const int swz8 = (lane & 7) << 3;             // ushort-idx XOR (== (row&7)<<3)

  f32x4 acc[4][4];
#pragma unroll
  for (int i = 0; i < 4; ++i)
#pragma unroll
    for (int j = 0; j < 4; ++j) {
      f32x4 z = {0.f, 0.f, 0.f, 0.f};
      acc[i][j] = z;
    }
  half8 a[4], b[4];

#define DS_A(K)                                                             \
  _Pragma("unroll") for (int m = 0; m < 4; ++m) {                           \
    const int r = wr * 64 + m * 16 + fr;                                    \
    const int idx = (r * 64 + (K) * 32 + fk * 8) ^ swz8;                    \
    a[m] = *reinterpret_cast<const half8*>(Acur + idx);                     \
  }
#define DS_B(K)                                                             \
  _Pragma("unroll") for (int n = 0; n < 4; ++n) {                           \
    const int r = wc * 64 + n * 16 + fr;                                    \
    const int idx = (r * 64 + (K) * 32 + fk * 8) ^ swz8;                    \
    b[n] = *reinterpret_cast<const half8*>(Bcur + idx);                     \
  }
#define MFMA_PH()                                                           \
  __builtin_amdgcn_s_setprio(1);                                            \
  _Pragma("unroll") for (int i = 0; i < 4; ++i)                             \
  _Pragma("unroll") for (int j = 0; j < 4; ++j)                             \
    acc[i][j] = __builtin_amdgcn_mfma_f32_16x16x32_f16(a[i], b[j], acc[i][j], 0, 0, 0); \
  __builtin_amdgcn_s_setprio(0);
#define STAGE_A(Q)                                                          \
  gload_lds16(Ah + (size_t)(rowA0 + (Q) * 128 + st_row) * 1024 + k0 + st_src * 8, \
              Lnxt + ((Q) * 128 + st_row) * 64 + st_unit * 8)
#define STAGE_B(Q)                                                          \
  gload_lds16(Bh + (size_t)(rowB0 + (Q) * 128 + st_row) * 1024 + k0 + st_src * 8, \
              Lnxt + 16384 + ((Q) * 128 + st_row) * 64 + st_unit * 8)
#define BAR() __builtin_amdgcn_s_barrier()

  // prologue: stage tile 0 into buf0
  int k0 = 0;
  ushort* Lnxt = smem;
  STAGE_A(0); STAGE_A(1); STAGE_B(0); STAGE_B(1);
  asm volatile("s_waitcnt vmcnt(0)" ::: "memory");
  BAR();

#pragma unroll 1
  for (int t = 0; t < NTILES - 1; ++t) {
    const int cur = t & 1;
    const ushort* Acur = smem + cur * 32768;
    const ushort* Bcur = Acur + 16384;
    Lnxt = smem + (cur ^ 1) * 32768;
    k0 = (t + 1) << 6;

    // phase 1 (k=0): reads + all staging issued early
    DS_A(0); DS_B(0);
    STAGE_A(0); STAGE_A(1); STAGE_B(0); STAGE_B(1);
    BAR();
    MFMA_PH();
    BAR();
    // phase 2 (k=1)
    DS_A(1); DS_B(1);
    BAR();
    MFMA_PH();
    asm volatile("s_waitcnt vmcnt(0)" ::: "memory");
    BAR();
  }

  // epilogue tile (no staging)
  {
    const ushort* Acur = smem + ((NTILES - 1) & 1) * 32768;
    const ushort* Bcur = Acur + 16384;
    DS_A(0); DS_B(0);
    BAR();
    MFMA_PH();
    BAR();
    DS_A(1); DS_B(1);
    BAR();
    MFMA_PH();
  }

  // ---- epilogue: LDS-aggregated candidate push (reuse dead smem) ----
  char* sb = reinterpret_cast<char*>(smem);
  int*    lcnt  = reinterpret_cast<int*>(sb);            // [256]
  float2* lcand = reinterpret_cast<float2*>(sb + 1024);  // [256][SLOT] = 64 KB

  __syncthreads();
  if (tid < 256) lcnt[tid] = 0;
  __syncthreads();

  const int ccol = lane & 15;
  const int crow = (lane >> 4) * 4;
#pragma unroll
  for (int j = 0; j < 4; ++j) {
    const int col = tn * 256 + wc * 64 + j * 16 + ccol;
    const float bv = bias[col];
#pragma unroll
    for (int i = 0; i < 4; ++i) {
      const int lrow0 = wr * 64 + i * 16 + crow;
#pragma unroll
      for (int p = 0; p < 4; ++p) {
        const float v = acc[i][j][p] + bv;
        if (v >= TAU) {
          const int lrow = lrow0 + p;
          const int pos = atomicAdd(&lcnt[lrow], 1);
          if (pos < SLOT)
            lcand[lrow * SLOT + pos] = make_float2(v, __int_as_float(col));
        }
      }
    }
  }
  __syncthreads();

  if (tid < 256) {
    int c = lcnt[tid];
    const int grow = strm * B_ROWS + rowA0 + tid;   // global row id (both streams)
    if (c > SLOT) { flags[grow] = 1; c = SLOT; }
    if (c > 0) {
      const int base = atomicAdd(&cnt[grow], c);
      float2* dst = cand + (size_t)grow * CAND_CAP;
      for (int k = 0; k < c; ++k) {
        const int pos = base + k;
        if (pos < CAND_CAP) dst[pos] = lcand[tid * SLOT + k];
      }
      // if base+c > CAND_CAP, cnt[grow] ends > CAND_CAP -> topk flags the row
    }
  }
#undef DS_A
#undef DS_B
#undef MFMA_PH
#undef STAGE_A
#undef STAGE_B
#undef BAR
}

// ---------------- top-K from candidates + refinement + latent + DECODE -------
// One block (256 thr) per (stream, row) = 8192 blocks.  Select exact top-32
// (radix -> window -> exact f64 refinement, jax tie-break), write dense latent
// (zeros + 32), then compute recon = b_dec + sum val*Wdec[idx] directly from
// the in-LDS selection (decode fused; no cvals/cidx round trip).
__global__ __launch_bounds__(256) void topk_decode_kernel(
    const float2* __restrict__ cand, const int* __restrict__ cnt,
    int* __restrict__ flags,
    float* __restrict__ latent0, float* __restrict__ latent1,
    float* __restrict__ recon0, float* __restrict__ recon1,
    const float* __restrict__ X0, const float* __restrict__ X1,
    const float* __restrict__ WT0, const float* __restrict__ WT1,
    const float* __restrict__ be0, const float* __restrict__ be1,
    const float* __restrict__ Wd0, const float* __restrict__ Wd1,
    const float* __restrict__ bd0, const float* __restrict__ bd1) {
  __shared__ float    sval[CAND_CAP];
  __shared__ int      sidx[CAND_CAP];
  __shared__ uint32_t hist[2048];
  __shared__ uint32_t chunkS[256];
  __shared__ float    swval[WCAP];
  __shared__ int      swidx[WCAP];
  __shared__ double   wexact[WCAP];
  __shared__ float    sel_val[K_TOP];
  __shared__ int      sel_idx[K_TOP];
  __shared__ uint32_t s_d, s_ab;
  __shared__ int      s_ndef, s_nw, s_bad;

  const int tid  = threadIdx.x;
  const int grow = blockIdx.x;            // global row (stream-merged)
  const int strm = grow >> 12;
  const int row  = grow & (B_ROWS - 1);
  const int n = cnt[grow];

  float* latent = strm ? latent1 : latent0;
  float* recon  = strm ? recon1 : recon0;
  const float* X    = strm ? X1 : X0;
  const float* WT   = strm ? WT1 : WT0;
  const float* benc = strm ? be1 : be0;
  const float* Wdec = strm ? Wd1 : Wd0;
  const float* bdec = strm ? bd1 : bd0;

  if (n < K_TOP || n > CAND_CAP) {
    if (tid == 0) flags[grow] = 1;
    return;
  }

  const float2* crow = cand + (size_t)grow * CAND_CAP;
  for (int i = tid; i < n; i += 256) {
    const float2 c = crow[i];
    sval[i] = c.x;
    sidx[i] = __float_as_int(c.y);
  }
  __syncthreads();

  // ---- 2-level radix on candidate f32 bits (all values >= TAU > 0) ----
  uint32_t prefTop = 0, d1 = 0, needL = K_TOP;
#pragma unroll 1
  for (int level = 0; level < 2; ++level) {
    const int shift = level ? 9 : 20;
    for (int b = tid; b < 2048; b += 256) hist[b] = 0;
    __syncthreads();
    for (int i = tid; i < n; i += 256) {
      const uint32_t k = __float_as_uint(sval[i]);
      if (level == 0 || (k >> 20) == prefTop)
        atomicAdd(&hist[(k >> shift) & 2047], 1u);
    }
    __syncthreads();
    uint32_t cs = 0;
#pragma unroll
    for (int c = 0; c < 8; ++c) cs += hist[tid * 8 + c];
    chunkS[tid] = cs;
    __syncthreads();
    for (int off = 1; off < 256; off <<= 1) {
      const uint32_t v = (tid + off < 256) ? chunkS[tid + off] : 0u;
      __syncthreads();
      chunkS[tid] += v;
      __syncthreads();
    }
    {
      uint32_t cum = (tid + 1 < 256) ? chunkS[tid + 1] : 0u;
#pragma unroll
      for (int c = 7; c >= 0; --c) {
        const int bb = tid * 8 + c;
        const uint32_t nxt = cum;
        cum += hist[bb];
        if (cum >= needL && nxt < needL) { s_d = (uint32_t)bb; s_ab = nxt; }
      }
    }
    __syncthreads();
    if (level == 0) { prefTop = s_d; needL = needL - s_ab; }
    else            { d1 = s_d; }
    __syncthreads();
  }

  const uint32_t blo_bits = (prefTop << 20) | (d1 << 9);
  const float Tlo = __uint_as_float(blo_bits);
  const float Thi = __uint_as_float(blo_bits + 512u);
  const float Tp = Thi + TK_DELTA;
  const float Tm = Tlo - TK_DELTA;

  if (Tm < TAU) {   // window extends below candidate floor (never expected)
    if (tid == 0) flags[grow] = 1;
    return;
  }

  // ---- classify candidates: definite-in / window ----
  if (tid == 0) { s_ndef = 0; s_nw = 0; s_bad = 0; }
  __syncthreads();
  for (int i = tid; i < n; i += 256) {
    const float v = sval[i];
    if (v > Tp) {
      const int pos = atomicAdd(&s_ndef, 1);
      if (pos < K_TOP) { sel_val[pos] = v; sel_idx[pos] = sidx[i]; }
      else             { s_bad = 1; }
    } else if (v >= Tm) {
      const int pos = atomicAdd(&s_nw, 1);
      if (pos < WCAP) { swval[pos] = v; swidx[pos] = sidx[i]; }
      else            { s_bad = 1; }
    }
  }
  __syncthreads();
  const int ndef = s_ndef;
  const int nw   = s_nw;
  if (s_bad || ndef >= K_TOP) {
    if (tid == 0) flags[grow] = 1;
    return;
  }
  const int r = K_TOP - ndef;     // >= 1

  // ---- exact f64 refinement of window members ----
  {
    const int wv = tid >> 6, ln = tid & 63;
    const float* xr = X + (size_t)row * D_IN;
    for (int c = wv; c < nw; c += 4) {
      const float* wrp = WT + (size_t)swidx[c] * D_IN;
      double a = 0.0;
#pragma unroll
      for (int j = 0; j < 16; ++j)
        a += (double)xr[ln + 64 * j] * (double)wrp[ln + 64 * j];
#pragma unroll
      for (int off = 32; off; off >>= 1) a += __shfl_xor(a, off);
      if (ln == 0) wexact[c] = a + (double)benc[swidx[c]];
    }
  }
  __syncthreads();
  // rank window by (exact desc, index asc) = jax tie-break; take top r
  if (tid < nw) {
    const double ei = wexact[tid];
    const int    ii = swidx[tid];
    int rank = 0;
    for (int j = 0; j < nw; ++j) {
      const double ej = wexact[j];
      const int    ij = swidx[j];
      rank += (ej > ei) || (ej == ei && ij < ii);
    }
    if (rank < r) { sel_val[ndef + rank] = swval[tid]; sel_idx[ndef + rank] = ii; }
  }
  __syncthreads();

  // ---- dense latent row: zeros + 32 selected ----
  float* rowp = latent + (size_t)row * H_HID;
  const float4 z4 = make_float4(0.f, 0.f, 0.f, 0.f);
  for (int i4 = tid; i4 < H_HID / 4; i4 += 256)
    reinterpret_cast<float4*>(rowp)[i4] = z4;
  __syncthreads();   // zeros complete BEFORE scatter
  if (tid < K_TOP) rowp[sel_idx[tid]] = sel_val[tid];

  // ---- fused decode: recon = b_dec + sum_k val_k * Wdec[idx_k, :] ----
  const float4 b4 = reinterpret_cast<const float4*>(bdec)[tid];
  float ax = b4.x, ay = b4.y, az = b4.z, aw = b4.w;
#pragma unroll 1
  for (int k = 0; k < K_TOP; ++k) {
    const float v = sel_val[k];
    const float4 w = reinterpret_cast<const float4*>(Wdec + (size_t)sel_idx[k] * D_IN)[tid];
    ax = fmaf(v, w.x, ax);
    ay = fmaf(v, w.y, ay);
    az = fmaf(v, w.z, az);
    aw = fmaf(v, w.w, aw);
  }
  reinterpret_cast<float4*>(recon + (size_t)row * D_IN)[tid] = make_float4(ax, ay, az, aw);
}

// ---------------- exact fallback (expected-never path) ----------------
// One block per (stream,row); immediate exit when flag==0.  Flagged rows:
// exact f64 row in 128KB dynamic LDS, top-32 by (value desc, idx asc), write
// latent row + recon.  Bit-exact.
__global__ __launch_bounds__(256) void fallback_kernel(
    const int* __restrict__ flags,
    const float* __restrict__ X0, const float* __restrict__ X1,
    const float* __restrict__ WT0, const float* __restrict__ WT1,
    const float* __restrict__ be0, const float* __restrict__ be1,
    float* __restrict__ latent0, float* __restrict__ latent1,
    float* __restrict__ recon0, float* __restrict__ recon1,
    const float* __restrict__ Wd0, const float* __restrict__ Wd1,
    const float* __restrict__ bd0, const float* __restrict__ bd1) {
  extern __shared__ double sc[];   // [H_HID] doubles = 128 KB dynamic
  __shared__ double rb[256];
  __shared__ int    ri[256];
  __shared__ float  fsel_val[K_TOP];
  __shared__ int    fsel_idx[K_TOP];
  const int grow = blockIdx.x;
  if (flags[grow] == 0) return;
  const int strm = grow >> 12;
  const int row  = grow & (B_ROWS - 1);
  const int tid = threadIdx.x;
  const float* X    = strm ? X1 : X0;
  const float* WT   = strm ? WT1 : WT0;
  const float* benc = strm ? be1 : be0;
  float* latent = strm ? latent1 : latent0;
  float* recon  = strm ? recon1 : recon0;
  const float* Wdec = strm ? Wd1 : Wd0;
  const float* bdec = strm ? bd1 : bd0;

  const float* xr = X + (size_t)row * D_IN;
  for (int c = tid; c < H_HID; c += 256) {
    const float* wrp = WT + (size_t)c * D_IN;
    double a = (double)benc[c];
    for (int j = 0; j < D_IN; ++j)
      a += (double)xr[j] * (double)wrp[j];
    sc[c] = fmax(a, 0.0);   // relu
  }
  float* rowp = latent + (size_t)row * H_HID;
  for (int i = tid; i < H_HID; i += 256) rowp[i] = 0.0f;
  __syncthreads();
#pragma unroll 1
  for (int k = 0; k < K_TOP; ++k) {
    double bv = -1.0; int bi = H_HID;
    for (int c = tid; c < H_HID; c += 256) {
      const double v = sc[c];
      if (v > bv || (v == bv && c < bi)) { bv = v; bi = c; }
    }
    rb[tid] = bv; ri[tid] = bi;
    __syncthreads();
    for (int off = 128; off; off >>= 1) {
      if (tid < off) {
        if (rb[tid + off] > rb[tid] ||
            (rb[tid + off] == rb[tid] && ri[tid + off] < ri[tid])) {
          rb[tid] = rb[tid + off]; ri[tid] = ri[tid + off];
        }
      }
      __syncthreads();
    }
    if (tid == 0) {
      const int ii = ri[0];
      const float vv = (float)rb[0];
      fsel_val[k] = vv; fsel_idx[k] = ii;
      rowp[ii] = vv;
      sc[ii] = -1.0;
    }
    __syncthreads();
  }
  // recon for this row
  const float4 b4 = reinterpret_cast<const float4*>(bdec)[tid];
  float ax = b4.x, ay = b4.y, az = b4.z, aw = b4.w;
#pragma unroll 1
  for (int k = 0; k < K_TOP; ++k) {
    const float v = fsel_val[k];
    const float4 w = reinterpret_cast<const float4*>(Wdec + (size_t)fsel_idx[k] * D_IN)[tid];
    ax = fmaf(v, w.x, ax);
    ay = fmaf(v, w.y, ay);
    az = fmaf(v, w.z, az);
    aw = fmaf(v, w.w, aw);
  }
  reinterpret_cast<float4*>(recon + (size_t)row * D_IN)[tid] = make_float4(ax, ay, az, aw);
}

// ---------------- launch ----------------

extern "C" void kernel_launch(void* const* d_in, const int* in_sizes, int n_in,
                              void* d_out, int out_size, void* d_ws, size_t ws_size,
                              hipStream_t stream) {
  (void)in_sizes; (void)n_in; (void)out_size; (void)ws_size;
  const float* Xv     = (const float*)d_in[0];
  const float* Xt     = (const float*)d_in[1];
  const float* Wv_enc = (const float*)d_in[2];
  const float* bv_enc = (const float*)d_in[3];
  const float* Wt_enc = (const float*)d_in[4];
  const float* bt_enc = (const float*)d_in[5];
  const float* Wv_dec = (const float*)d_in[6];
  const float* bv_dec = (const float*)d_in[7];
  const float* Wt_dec = (const float*)d_in[8];
  const float* bt_dec = (const float*)d_in[9];

  float* out      = (float*)d_out;
  float* recon_v  = out;
  float* recon_t  = out + (size_t)B_ROWS * D_IN;
  float* latent_v = out + 2ull * B_ROWS * D_IN;
  float* latent_t = latent_v + (size_t)B_ROWS * H_HID;

  char* ws = (char*)d_ws;
  const size_t szA = (size_t)B_ROWS * D_IN;    // 4M elems
  const size_t szB = (size_t)H_HID * D_IN;     // 16M elems
  const size_t szC = (size_t)B_ROWS * CAND_CAP;
  ushort* Ah_v  = (ushort*)ws;
  ushort* Ah_t  = Ah_v + szA;
  ushort* Bh_v  = Ah_t + szA;
  ushort* Bh_t  = Bh_v + szB;
  float*  WT32_v = (float*)(Bh_t + szB);
  float*  WT32_t = WT32_v + szB;
  float2* cand  = (float2*)(WT32_t + szB);     // [2*B_ROWS][CAND_CAP]
  int*    cnt   = (int*)(cand + 2 * szC);      // [2*B_ROWS]
  int*    flags = cnt + 2 * B_ROWS;            // [2*B_ROWS]

  hipFuncSetAttribute((const void*)gemm_enc_2ph,
                      hipFuncAttributeMaxDynamicSharedMemorySize, 131072);
  hipFuncSetAttribute((const void*)fallback_kernel,
                      hipFuncAttributeMaxDynamicSharedMemorySize, 131072);

  // zero counters + flags (contiguous 64 KB)
  hipMemsetAsync(cnt, 0, 4 * B_ROWS * sizeof(int), stream);

  // splits (both streams per dispatch)
  split_a_kernel<<<2 * (B_ROWS * D_IN / 1024), 256, 0, stream>>>(Xv, Xt, Ah_v, Ah_t);
  split_wt_kernel<<<dim3(H_HID / 32, D_IN / 32, 2), dim3(32, 8), 0, stream>>>(
      Wv_enc, Wt_enc, Bh_v, Bh_t, WT32_v, WT32_t);

  // encoder GEMMs (both streams, one dispatch)
  gemm_enc_2ph<<<2048, 1024, 131072, stream>>>(Ah_v, Ah_t, Bh_v, Bh_t,
                                               bv_enc, bt_enc, cand, cnt, flags);

  // top-K + refinement + latent + fused decode (both streams)
  topk_decode_kernel<<<2 * B_ROWS, 256, 0, stream>>>(
      cand, cnt, flags, latent_v, latent_t, recon_v, recon_t,
      Xv, Xt, WT32_v, WT32_t, bv_enc, bt_enc,
      Wv_dec, Wt_dec, bv_dec, bt_dec);

  // exact fallback for flagged rows (expected none)
  fallback_kernel<<<2 * B_ROWS, 256, 131072, stream>>>(
      flags, Xv, Xt, WT32_v, WT32_t, bv_enc, bt_enc,
      latent_v, latent_t, recon_v, recon_t,
      Wv_dec, Wt_dec, bv_dec, bt_dec);
}

// Round 13
// 689.173 us; speedup vs baseline: 3.0104x; 1.0017x over previous
//
#include <hip/hip_runtime.h>
#include <hip/hip_fp16.h>
#include <stdint.h>

#define B_ROWS 4096
#define D_IN   1024
#define H_HID  16384
#define K_TOP  32

#define CAND_CAP 1536     // per-row candidate capacity (mean 682, sigma 26)
#define SLOT     32       // per-(row, 256-col tile) slots (mean 10.7, sigma 3.3)
#define TAU      1.0f     // fixed candidate threshold; safety via flags+fallback
#define TK_DELTA 1e-2f    // refinement window half-width (>= 2x 12-sigma h~ error)
#define WCAP     256

typedef __attribute__((ext_vector_type(8))) _Float16 half8;
typedef __attribute__((ext_vector_type(4))) float    f32x4;

// ---------------- helpers ----------------

__device__ __forceinline__ ushort hi16(float x) {
  return (fabsf(x) >= 0x1p-14f) ? __half_as_ushort(__float2half(x)) : (ushort)0;
}

__device__ __forceinline__ void gload_lds16(const void* g, void* l) {
  __builtin_amdgcn_global_load_lds(
      (const __attribute__((address_space(1))) void*)g,
      (__attribute__((address_space(3))) void*)l, 16, 0, 0);
}

// ---------------- fused prep: split_wt + split_a + counter zero ----------------
// grid: [0, 32768) split_wt | [32768, 40960) split_a | [40960, 41024) zero
__global__ __launch_bounds__(256) void prep_kernel(
    const float* __restrict__ W0, const float* __restrict__ W1,
    ushort* __restrict__ hiT0, ushort* __restrict__ hiT1,
    float* __restrict__ wT0, float* __restrict__ wT1,
    const float* __restrict__ x0, const float* __restrict__ x1,
    ushort* __restrict__ hiA0, ushort* __restrict__ hiA1,
    int* __restrict__ zbase) {
  __shared__ float tile[32][33];
  const int b = blockIdx.x;
  const int tid = threadIdx.x;
  if (b < 32768) {                      // ---- W transpose + split ----
    const int s  = b >> 14;
    const int b2 = b & 16383;           // 512 x 32
    const float* W = s ? W1 : W0;
    ushort* hiT = s ? hiT1 : hiT0;
    float*  wT32 = s ? wT1 : wT0;
    const int c0 = (b2 & 511) * 32;
    const int r0 = (b2 >> 9) * 32;
    const int tx = tid & 31;
    const int ty = tid >> 5;
#pragma unroll
    for (int i = 0; i < 32; i += 8)
      tile[ty + i][tx] = W[(size_t)(r0 + ty + i) * H_HID + c0 + tx];
    __syncthreads();
#pragma unroll
    for (int i = 0; i < 32; i += 8) {
      float v = tile[tx][ty + i];
      size_t o = (size_t)(c0 + ty + i) * D_IN + r0 + tx;
      hiT[o]  = hi16(v);
      wT32[o] = v;
    }
  } else if (b < 40960) {               // ---- X split ----
    const int idx = b - 32768;          // 0..8191; 4096 per stream
    const int s = idx >> 12;
    const float* x = s ? x1 : x0;
    ushort* hi = s ? hiA1 : hiA0;
    const int t = (idx & 4095) * 256 + tid;
    const int base = t * 4;
    float4 v = *reinterpret_cast<const float4*>(x + base);
    ushort4 h;
    h.x = hi16(v.x); h.y = hi16(v.y); h.z = hi16(v.z); h.w = hi16(v.w);
    *reinterpret_cast<ushort4*>(hi + base) = h;
  } else {                              // ---- zero cnt + flags (16384 ints) ----
    const int idx = (b - 40960) * 256 + tid;
    zbase[idx] = 0;
  }
}

// ---------------- encoder GEMM: 256x256 tiles, 8-phase, persistent J=8 -------
// 256 blocks = ONE round on 256 CUs (R12 bug: launched 512 with tng in [0,16)
// but there are only 64 tn tiles -> 8 groups; OOB B reads flooded cnt ->
// all-row fallback -> watchdog abort).  Each block: fixed tm, sweeps 8
// consecutive tn tiles; K-pipeline runs CONTINUOUSLY across tile boundaries
// (t=15 stages next tile's k0=0; counted-vmcnt ledger unchanged: 4@ph2,
// 2@ph4 -- vmcnt retires in issue order so epilogue stores only strengthen
// the waits).  Epilogue scratch = buf1 (consumed parity at t=15; in-flight
// stages target buf0); lcand transposed [SLOT][256] = conflict-free.
#define NTILES 16   // 1024 / 64
#define JTILES 8

__global__ __launch_bounds__(512, 2) void gemm_enc_8ph(const ushort* __restrict__ Ah0,
                                                       const ushort* __restrict__ Ah1,
                                                       const ushort* __restrict__ Bh0,
                                                       const ushort* __restrict__ Bh1,
                                                       const float* __restrict__ bias0,
                                                       const float* __restrict__ bias1,
                                                       float2* __restrict__ cand,
                                                       int* __restrict__ cnt,
                                                       int* __restrict__ flags) {
  extern __shared__ ushort smem[];   // [2][32768]: buf*32768, B-half at +16384
  __shared__ int lcnt[256];          // epilogue row counters (static, +1KB)
  const int tid  = threadIdx.x;
  const int wid  = tid >> 6;
  const int lane = tid & 63;
  const int wr   = wid >> 2;
  const int wc   = wid & 3;
  const int strm = blockIdx.x >> 7;            // 128 blocks per stream
  const int bid  = blockIdx.x & 127;
  const ushort* Ah = strm ? Ah1 : Ah0;
  const ushort* Bh = strm ? Bh1 : Bh0;
  const float* bias = strm ? bias1 : bias0;
  const int tm   = bid & 15;                   // 0..15
  const int tng  = bid >> 4;                   // 0..7 (group of 8 tn)
  const int rowA0 = tm * 256;

  const int st_row = wid * 8 + (lane >> 3);
  const int st_lin = lane & 7;
  const int st_src = (lane & 7) ^ ((lane >> 3) & 7);
  const int fr   = lane & 15;
  const int fk   = lane >> 4;
  const int swz8 = (lane & 7) << 3;

  f32x4 acc[8][4];
#pragma unroll
  for (int i = 0; i < 8; ++i)
#pragma unroll
    for (int j = 0; j < 4; ++j) {
      f32x4 z = {0.f, 0.f, 0.f, 0.f};
      acc[i][j] = z;
    }
  half8 a[4][2], b[4][2];

#define DS_A(MH)                                                            \
  _Pragma("unroll") for (int m = 0; m < 4; ++m)                             \
  _Pragma("unroll") for (int k = 0; k < 2; ++k) {                           \
    const int r = wr * 128 + ((MH) * 4 + m) * 16 + fr;                      \
    const int idx = (r * 64 + k * 32 + fk * 8) ^ swz8;                      \
    a[m][k] = *reinterpret_cast<const half8*>(Acur + idx);                  \
  }
#define DS_B(NH)                                                            \
  _Pragma("unroll") for (int n = 0; n < 2; ++n)                             \
  _Pragma("unroll") for (int k = 0; k < 2; ++k) {                           \
    const int r = wc * 64 + ((NH) * 2 + n) * 16 + fr;                       \
    const int idx = (r * 64 + k * 32 + fk * 8) ^ swz8;                      \
    b[(NH) * 2 + n][k] = *reinterpret_cast<const half8*>(Bcur + idx);       \
  }
#define MFMA_PH(MH, NH)                                                     \
  __builtin_amdgcn_s_setprio(1);                                            \
  _Pragma("unroll") for (int m = 0; m < 4; ++m)                             \
  _Pragma("unroll") for (int n = 0; n < 2; ++n)                             \
  _Pragma("unroll") for (int k = 0; k < 2; ++k)                             \
    acc[(MH) * 4 + m][(NH) * 2 + n] = __builtin_amdgcn_mfma_f32_16x16x32_f16( \
        a[m][k], b[(NH) * 2 + n][k], acc[(MH) * 4 + m][(NH) * 2 + n], 0, 0, 0); \
  __builtin_amdgcn_s_setprio(0);
#define STAGE_A(Q)                                                          \
  gload_lds16(Ah + (size_t)(rowA0 + (Q) * 64 + st_row) * 1024 + st_k0 + st_src * 8, \
              Lnxt + ((Q) * 64 + st_row) * 64 + st_lin * 8)
#define STAGE_B(Q)                                                          \
  gload_lds16(Bh + (size_t)(st_rowB0 + (Q) * 64 + st_row) * 1024 + st_k0 + st_src * 8, \
              Lnxt + 16384 + ((Q) * 64 + st_row) * 64 + st_lin * 8)
#define BAR() __builtin_amdgcn_s_barrier()

  // prologue: stage (j=0, t=0) into buf0.  Order: Bq0..3, Aq0, Aq2, Aq1, Aq3.
  {
    const int st_k0 = 0;
    const int st_rowB0 = tng * 8 * 256;
    ushort* Lnxt = smem;
    STAGE_B(0); STAGE_B(1); STAGE_B(2); STAGE_B(3);
    STAGE_A(0); STAGE_A(2); STAGE_A(1); STAGE_A(3);
  }
  asm volatile("s_waitcnt vmcnt(2)" ::: "memory");
  BAR();

#pragma unroll 1
  for (int jt = 0; jt < JTILES * NTILES; ++jt) {
    const int t = jt & (NTILES - 1);
    const int j = jt >> 4;
    const int cur = t & 1;                     // NTILES even -> parity by t
    const ushort* Acur = smem + cur * 32768;
    const ushort* Bcur = Acur + 16384;
    ushort* Lnxt = smem + (cur ^ 1) * 32768;
    int tt = t + 1, jn = j;
    if (tt == NTILES) { tt = 0; jn = j + 1; }
    const bool hn = (jn < JTILES);
    const int st_k0 = tt << 6;
    const int st_rowB0 = (tng * 8 + jn) * 256;

    // phase 1
    DS_A(0); DS_B(0);
    if (hn) { STAGE_B(0); STAGE_B(1); }
    BAR();
    MFMA_PH(0, 0);
    BAR();
    // phase 2
    DS_B(1);
    if (hn) { STAGE_B(2); STAGE_B(3); }
    BAR();
    MFMA_PH(0, 1);
    asm volatile("s_waitcnt vmcnt(4)" ::: "memory");
    BAR();
    // phase 3
    DS_A(1);
    if (hn) { STAGE_A(0); STAGE_A(2); }
    BAR();
    MFMA_PH(1, 0);
    BAR();
    // phase 4
    if (hn) { STAGE_A(1); STAGE_A(3); }
    BAR();
    MFMA_PH(1, 1);
    asm volatile("s_waitcnt vmcnt(2)" ::: "memory");
    BAR();

    if (t == NTILES - 1) {
      // ---- candidate epilogue for tile (tm, tn = tng*8+j) ----
      // scratch = buf1 (cur==1 here, fully consumed; in-flight stages -> buf0)
      const int tn = tng * 8 + j;
      float2* lcand = reinterpret_cast<float2*>(smem + 32768);  // [SLOT][256]
      if (tid < 256) lcnt[tid] = 0;
      __syncthreads();

      const int ccol = lane & 15;
      const int crow = (lane >> 4) * 4;
#pragma unroll
      for (int jj = 0; jj < 4; ++jj) {
        const int col = tn * 256 + wc * 64 + jj * 16 + ccol;
        const float bv = bias[col];
#pragma unroll
        for (int i = 0; i < 8; ++i) {
          const int lrow0 = wr * 128 + i * 16 + crow;
#pragma unroll
          for (int p = 0; p < 4; ++p) {
            const float v = acc[i][jj][p] + bv;
            if (v >= TAU) {
              const int lrow = lrow0 + p;
              const int pos = atomicAdd(&lcnt[lrow], 1);
              if (pos < SLOT)
                lcand[pos * 256 + lrow] = make_float2(v, __int_as_float(col));
            }
          }
        }
      }
      __syncthreads();

      if (tid < 256) {
        int c = lcnt[tid];
        const int grow = strm * B_ROWS + rowA0 + tid;
        if (c > SLOT) { flags[grow] = 1; c = SLOT; }
        if (c > 0) {
          const int base = atomicAdd(&cnt[grow], c);
          float2* dst = cand + (size_t)grow * CAND_CAP;
          for (int k = 0; k < c; ++k) {
            const int pos = base + k;
            if (pos < CAND_CAP) dst[pos] = lcand[k * 256 + tid];
          }
        }
      }
      // reset accumulators for the next tile
#pragma unroll
      for (int i = 0; i < 8; ++i)
#pragma unroll
        for (int jj = 0; jj < 4; ++jj) {
          f32x4 z = {0.f, 0.f, 0.f, 0.f};
          acc[i][jj] = z;
        }
      __syncthreads();   // lcand reads done before buf1 is restaged (next t=0 ph1)
    }
  }
#undef DS_A
#undef DS_B
#undef MFMA_PH
#undef STAGE_A
#undef STAGE_B
#undef BAR
}

// ---------------- top-K from candidates + refinement + latent + DECODE -------
__global__ __launch_bounds__(256) void topk_decode_kernel(
    const float2* __restrict__ cand, const int* __restrict__ cnt,
    int* __restrict__ flags,
    float* __restrict__ latent0, float* __restrict__ latent1,
    float* __restrict__ recon0, float* __restrict__ recon1,
    const float* __restrict__ X0, const float* __restrict__ X1,
    const float* __restrict__ WT0, const float* __restrict__ WT1,
    const float* __restrict__ be0, const float* __restrict__ be1,
    const float* __restrict__ Wd0, const float* __restrict__ Wd1,
    const float* __restrict__ bd0, const float* __restrict__ bd1) {
  __shared__ float    sval[CAND_CAP];
  __shared__ int      sidx[CAND_CAP];
  __shared__ uint32_t hist[2048];
  __shared__ uint32_t chunkS[256];
  __shared__ float    swval[WCAP];
  __shared__ int      swidx[WCAP];
  __shared__ double   wexact[WCAP];
  __shared__ float    sel_val[K_TOP];
  __shared__ int      sel_idx[K_TOP];
  __shared__ uint32_t s_d, s_ab;
  __shared__ int      s_ndef, s_nw, s_bad;

  const int tid  = threadIdx.x;
  const int grow = blockIdx.x;
  const int strm = grow >> 12;
  const int row  = grow & (B_ROWS - 1);
  const int n = cnt[grow];

  float* latent = strm ? latent1 : latent0;
  float* recon  = strm ? recon1 : recon0;
  const float* X    = strm ? X1 : X0;
  const float* WT   = strm ? WT1 : WT0;
  const float* benc = strm ? be1 : be0;
  const float* Wdec = strm ? Wd1 : Wd0;
  const float* bdec = strm ? bd1 : bd0;

  if (n < K_TOP || n > CAND_CAP) {
    if (tid == 0) flags[grow] = 1;
    return;
  }

  const float2* crow = cand + (size_t)grow * CAND_CAP;
  for (int i = tid; i < n; i += 256) {
    const float2 c = crow[i];
    sval[i] = c.x;
    sidx[i] = __float_as_int(c.y);
  }
  __syncthreads();

  // ---- 2-level radix on candidate f32 bits (all values >= TAU > 0) ----
  uint32_t prefTop = 0, d1 = 0, needL = K_TOP;
#pragma unroll 1
  for (int level = 0; level < 2; ++level) {
    const int shift = level ? 9 : 20;
    for (int b = tid; b < 2048; b += 256) hist[b] = 0;
    __syncthreads();
    for (int i = tid; i < n; i += 256) {
      const uint32_t k = __float_as_uint(sval[i]);
      if (level == 0 || (k >> 20) == prefTop)
        atomicAdd(&hist[(k >> shift) & 2047], 1u);
    }
    __syncthreads();
    uint32_t cs = 0;
#pragma unroll
    for (int c = 0; c < 8; ++c) cs += hist[tid * 8 + c];
    chunkS[tid] = cs;
    __syncthreads();
    for (int off = 1; off < 256; off <<= 1) {
      const uint32_t v = (tid + off < 256) ? chunkS[tid + off] : 0u;
      __syncthreads();
      chunkS[tid] += v;
      __syncthreads();
    }
    {
      uint32_t cum = (tid + 1 < 256) ? chunkS[tid + 1] : 0u;
#pragma unroll
      for (int c = 7; c >= 0; --c) {
        const int bb = tid * 8 + c;
        const uint32_t nxt = cum;
        cum += hist[bb];
        if (cum >= needL && nxt < needL) { s_d = (uint32_t)bb; s_ab = nxt; }
      }
    }
    __syncthreads();
    if (level == 0) { prefTop = s_d; needL = needL - s_ab; }
    else            { d1 = s_d; }
    __syncthreads();
  }

  const uint32_t blo_bits = (prefTop << 20) | (d1 << 9);
  const float Tlo = __uint_as_float(blo_bits);
  const float Thi = __uint_as_float(blo_bits + 512u);
  const float Tp = Thi + TK_DELTA;
  const float Tm = Tlo - TK_DELTA;

  if (Tm < TAU) {
    if (tid == 0) flags[grow] = 1;
    return;
  }

  // ---- classify candidates: definite-in / window ----
  if (tid == 0) { s_ndef = 0; s_nw = 0; s_bad = 0; }
  __syncthreads();
  for (int i = tid; i < n; i += 256) {
    const float v = sval[i];
    if (v > Tp) {
      const int pos = atomicAdd(&s_ndef, 1);
      if (pos < K_TOP) { sel_val[pos] = v; sel_idx[pos] = sidx[i]; }
      else             { s_bad = 1; }
    } else if (v >= Tm) {
      const int pos = atomicAdd(&s_nw, 1);
      if (pos < WCAP) { swval[pos] = v; swidx[pos] = sidx[i]; }
      else            { s_bad = 1; }
    }
  }
  __syncthreads();
  const int ndef = s_ndef;
  const int nw   = s_nw;
  if (s_bad || ndef >= K_TOP) {
    if (tid == 0) flags[grow] = 1;
    return;
  }
  const int r = K_TOP - ndef;     // >= 1

  // ---- exact f64 refinement of window members ----
  {
    const int wv = tid >> 6, ln = tid & 63;
    const float* xr = X + (size_t)row * D_IN;
    for (int c = wv; c < nw; c += 4) {
      const float* wrp = WT + (size_t)swidx[c] * D_IN;
      double a = 0.0;
#pragma unroll
      for (int j = 0; j < 16; ++j)
        a += (double)xr[ln + 64 * j] * (double)wrp[ln + 64 * j];
#pragma unroll
      for (int off = 32; off; off >>= 1) a += __shfl_xor(a, off);
      if (ln == 0) wexact[c] = a + (double)benc[swidx[c]];
    }
  }
  __syncthreads();
  // rank window by (exact desc, index asc) = jax tie-break; take top r
  if (tid < nw) {
    const double ei = wexact[tid];
    const int    ii = swidx[tid];
    int rank = 0;
    for (int j = 0; j < nw; ++j) {
      const double ej = wexact[j];
      const int    ij = swidx[j];
      rank += (ej > ei) || (ej == ei && ij < ii);
    }
    if (rank < r) { sel_val[ndef + rank] = swval[tid]; sel_idx[ndef + rank] = ii; }
  }
  __syncthreads();

  // ---- dense latent row: zeros + 32 selected ----
  float* rowp = latent + (size_t)row * H_HID;
  const float4 z4 = make_float4(0.f, 0.f, 0.f, 0.f);
  for (int i4 = tid; i4 < H_HID / 4; i4 += 256)
    reinterpret_cast<float4*>(rowp)[i4] = z4;
  __syncthreads();   // zeros complete BEFORE scatter
  if (tid < K_TOP) rowp[sel_idx[tid]] = sel_val[tid];

  // ---- fused decode: recon = b_dec + sum_k val_k * Wdec[idx_k, :] ----
  const float4 b4 = reinterpret_cast<const float4*>(bdec)[tid];
  float ax = b4.x, ay = b4.y, az = b4.z, aw = b4.w;
#pragma unroll 1
  for (int k = 0; k < K_TOP; ++k) {
    const float v = sel_val[k];
    const float4 w = reinterpret_cast<const float4*>(Wdec + (size_t)sel_idx[k] * D_IN)[tid];
    ax = fmaf(v, w.x, ax);
    ay = fmaf(v, w.y, ay);
    az = fmaf(v, w.z, az);
    aw = fmaf(v, w.w, aw);
  }
  reinterpret_cast<float4*>(recon + (size_t)row * D_IN)[tid] = make_float4(ax, ay, az, aw);
}

// ---------------- exact fallback (expected-never path) ----------------
__global__ __launch_bounds__(256) void fallback_kernel(
    const int* __restrict__ flags,
    const float* __restrict__ X0, const float* __restrict__ X1,
    const float* __restrict__ WT0, const float* __restrict__ WT1,
    const float* __restrict__ be0, const float* __restrict__ be1,
    float* __restrict__ latent0, float* __restrict__ latent1,
    float* __restrict__ recon0, float* __restrict__ recon1,
    const float* __restrict__ Wd0, const float* __restrict__ Wd1,
    const float* __restrict__ bd0, const float* __restrict__ bd1) {
  extern __shared__ double sc[];   // [H_HID] doubles = 128 KB dynamic
  __shared__ double rb[256];
  __shared__ int    ri[256];
  __shared__ float  fsel_val[K_TOP];
  __shared__ int    fsel_idx[K_TOP];
  const int grow = blockIdx.x;
  if (flags[grow] == 0) return;
  const int strm = grow >> 12;
  const int row  = grow & (B_ROWS - 1);
  const int tid = threadIdx.x;
  const float* X    = strm ? X1 : X0;
  const float* WT   = strm ? WT1 : WT0;
  const float* benc = strm ? be1 : be0;
  float* latent = strm ? latent1 : latent0;
  float* recon  = strm ? recon1 : recon0;
  const float* Wdec = strm ? Wd1 : Wd0;
  const float* bdec = strm ? bd1 : bd0;

  const float* xr = X + (size_t)row * D_IN;
  for (int c = tid; c < H_HID; c += 256) {
    const float* wrp = WT + (size_t)c * D_IN;
    double a = (double)benc[c];
    for (int j = 0; j < D_IN; ++j)
      a += (double)xr[j] * (double)wrp[j];
    sc[c] = fmax(a, 0.0);   // relu
  }
  float* rowp = latent + (size_t)row * H_HID;
  for (int i = tid; i < H_HID; i += 256) rowp[i] = 0.0f;
  __syncthreads();
#pragma unroll 1
  for (int k = 0; k < K_TOP; ++k) {
    double bv = -1.0; int bi = H_HID;
    for (int c = tid; c < H_HID; c += 256) {
      const double v = sc[c];
      if (v > bv || (v == bv && c < bi)) { bv = v; bi = c; }
    }
    rb[tid] = bv; ri[tid] = bi;
    __syncthreads();
    for (int off = 128; off; off >>= 1) {
      if (tid < off) {
        if (rb[tid + off] > rb[tid] ||
            (rb[tid + off] == rb[tid] && ri[tid + off] < ri[tid])) {
          rb[tid] = rb[tid + off]; ri[tid] = ri[tid + off];
        }
      }
      __syncthreads();
    }
    if (tid == 0) {
      const int ii = ri[0];
      const float vv = (float)rb[0];
      fsel_val[k] = vv; fsel_idx[k] = ii;
      rowp[ii] = vv;
      sc[ii] = -1.0;
    }
    __syncthreads();
  }
  const float4 b4 = reinterpret_cast<const float4*>(bdec)[tid];
  float ax = b4.x, ay = b4.y, az = b4.z, aw = b4.w;
#pragma unroll 1
  for (int k = 0; k < K_TOP; ++k) {
    const float v = fsel_val[k];
    const float4 w = reinterpret_cast<const float4*>(Wdec + (size_t)fsel_idx[k] * D_IN)[tid];
    ax = fmaf(v, w.x, ax);
    ay = fmaf(v, w.y, ay);
    az = fmaf(v, w.z, az);
    aw = fmaf(v, w.w, aw);
  }
  reinterpret_cast<float4*>(recon + (size_t)row * D_IN)[tid] = make_float4(ax, ay, az, aw);
}

// ---------------- launch ----------------

extern "C" void kernel_launch(void* const* d_in, const int* in_sizes, int n_in,
                              void* d_out, int out_size, void* d_ws, size_t ws_size,
                              hipStream_t stream) {
  (void)in_sizes; (void)n_in; (void)out_size; (void)ws_size;
  const float* Xv     = (const float*)d_in[0];
  const float* Xt     = (const float*)d_in[1];
  const float* Wv_enc = (const float*)d_in[2];
  const float* bv_enc = (const float*)d_in[3];
  const float* Wt_enc = (const float*)d_in[4];
  const float* bt_enc = (const float*)d_in[5];
  const float* Wv_dec = (const float*)d_in[6];
  const float* bv_dec = (const float*)d_in[7];
  const float* Wt_dec = (const float*)d_in[8];
  const float* bt_dec = (const float*)d_in[9];

  float* out      = (float*)d_out;
  float* recon_v  = out;
  float* recon_t  = out + (size_t)B_ROWS * D_IN;
  float* latent_v = out + 2ull * B_ROWS * D_IN;
  float* latent_t = latent_v + (size_t)B_ROWS * H_HID;

  char* ws = (char*)d_ws;
  const size_t szA = (size_t)B_ROWS * D_IN;    // 4M elems
  const size_t szB = (size_t)H_HID * D_IN;     // 16M elems
  const size_t szC = (size_t)B_ROWS * CAND_CAP;
  ushort* Ah_v  = (ushort*)ws;
  ushort* Ah_t  = Ah_v + szA;
  ushort* Bh_v  = Ah_t + szA;
  ushort* Bh_t  = Bh_v + szB;
  float*  WT32_v = (float*)(Bh_t + szB);
  float*  WT32_t = WT32_v + szB;
  float2* cand  = (float2*)(WT32_t + szB);     // [2*B_ROWS][CAND_CAP]
  int*    cnt   = (int*)(cand + 2 * szC);      // [2*B_ROWS]
  int*    flags = cnt + 2 * B_ROWS;            // [2*B_ROWS]

  hipFuncSetAttribute((const void*)gemm_enc_8ph,
                      hipFuncAttributeMaxDynamicSharedMemorySize, 131072);
  hipFuncSetAttribute((const void*)fallback_kernel,
                      hipFuncAttributeMaxDynamicSharedMemorySize, 131072);

  // fused prep: W split/transpose + X split + counter zero (one dispatch)
  prep_kernel<<<41024, 256, 0, stream>>>(Wv_enc, Wt_enc, Bh_v, Bh_t, WT32_v, WT32_t,
                                         Xv, Xt, Ah_v, Ah_t, cnt);

  // encoder GEMMs (both streams, persistent J=8 blocks, single round)
  gemm_enc_8ph<<<256, 512, 131072, stream>>>(Ah_v, Ah_t, Bh_v, Bh_t,
                                             bv_enc, bt_enc, cand, cnt, flags);

  // top-K + refinement + latent + fused decode (both streams)
  topk_decode_kernel<<<2 * B_ROWS, 256, 0, stream>>>(
      cand, cnt, flags, latent_v, latent_t, recon_v, recon_t,
      Xv, Xt, WT32_v, WT32_t, bv_enc, bt_enc,
      Wv_dec, Wt_dec, bv_dec, bt_dec);

  // exact fallback for flagged rows (expected none)
  fallback_kernel<<<2 * B_ROWS, 256, 131072, stream>>>(
      flags, Xv, Xt, WT32_v, WT32_t, bv_enc, bt_enc,
      latent_v, latent_t, recon_v, recon_t,
      Wv_dec, Wt_dec, bv_dec, bt_dec);
}